// Round 1
// baseline (14297.507 us; speedup 1.0000x reference)
//
#include <hip/hip_runtime.h>
#include <hip/hip_bf16.h>
#include <math.h>

// ---------------- constants ----------------
#define D_MODEL   768
#define N_LAYER   8
#define D_INNER   1536
#define D_STATE   128
#define HEADDIM   64
#define NHEADS    24
#define CONV_DIM  1792
#define D_IN_PROJ 3352
#define AH        8
#define AD        64
#define AINNER    512
#define BSZ       2
#define SEQ       512
#define LC        64
#define ROWS      (BSZ*SEQ)          // 1024

__device__ __forceinline__ float siluf(float x) { return x / (1.f + expf(-x)); }

// block-wide sum, 256 threads (4 waves)
__device__ __forceinline__ float block_sum_256(float v, float* s4) {
    #pragma unroll
    for (int o = 32; o > 0; o >>= 1) v += __shfl_down(v, o, 64);
    __syncthreads();
    if ((threadIdx.x & 63) == 0) s4[threadIdx.x >> 6] = v;
    __syncthreads();
    return s4[0] + s4[1] + s4[2] + s4[3];
}

// ---------------- silu(mean(cond, axis=1)) ----------------
__global__ void k_silumean(const float* __restrict__ cond, float* __restrict__ smc) {
    int i = blockIdx.x * 256 + threadIdx.x;
    if (i >= BSZ * D_MODEL) return;
    int b = i / D_MODEL, d = i % D_MODEL;
    const float* p = cond + (size_t)b * LC * D_MODEL + d;
    float s = 0.f;
    #pragma unroll 4
    for (int l = 0; l < LC; l++) s += p[l * D_MODEL];
    s *= (1.f / (float)LC);
    smc[i] = siluf(s);
}

// ---------------- aff = smc @ ada_w + ada_b  (B x 4608) ----------------
__global__ void k_ada(const float* __restrict__ smc, const float* __restrict__ adaw,
                      const float* __restrict__ adab, float* __restrict__ aff) {
    int i = blockIdx.x * 256 + threadIdx.x;
    if (i >= BSZ * 4608) return;
    int b = i / 4608, j = i % 4608;
    const float* x = smc + b * D_MODEL;
    const float* w = adaw + j;
    float s = adab[j];
    for (int d = 0; d < D_MODEL; d++) s += x[d] * w[(size_t)d * 4608];
    aff[i] = s;
}

// ---------------- residual += hidden; rmsnorm; mod ----------------
__global__ void k_addrmsmod(const float* __restrict__ hin, float* __restrict__ residual,
                            const float* __restrict__ normw, const float* __restrict__ aff,
                            float* __restrict__ hidden_n, float* __restrict__ u) {
    __shared__ float s4[4];
    int row = blockIdx.x;
    int b = row >> 9;
    const float* hp = hin + (size_t)row * D_MODEL;
    float* rp = residual + (size_t)row * D_MODEL;
    float v[3]; float ss = 0.f;
    #pragma unroll
    for (int j = 0; j < 3; j++) {
        int d = threadIdx.x + j * 256;
        float x = hp[d] + rp[d];
        rp[d] = x; v[j] = x; ss += x * x;
    }
    ss = block_sum_256(ss, s4);
    float inv = rsqrtf(ss / (float)D_MODEL + 1e-5f);
    const float* sh = aff + b * 4608;         // sh_mba
    const float* sc = aff + b * 4608 + 768;   // sc_mba
    #pragma unroll
    for (int j = 0; j < 3; j++) {
        int d = threadIdx.x + j * 256;
        float hn = v[j] * inv * normw[d];
        hidden_n[(size_t)row * D_MODEL + d] = hn;
        u[(size_t)row * D_MODEL + d] = hn * (1.f + sc[d]) + sh[d];
    }
}

// ---------------- tiled fp32 GEMM: C[M,N] = A[M,K] @ B[K,N] ----------------
__global__ __launch_bounds__(256, 2)
void k_sgemm(const float* __restrict__ A, const float* __restrict__ B,
             float* __restrict__ C, int M, int N, int K) {
    __shared__ float As[8][128];
    __shared__ float Bs[8][128];
    int n0 = blockIdx.x * 128, m0 = blockIdx.y * 128;
    int tid = threadIdx.x;
    int tx = tid & 15, ty = tid >> 4;
    float acc[8][8];
    #pragma unroll
    for (int i = 0; i < 8; i++)
        #pragma unroll
        for (int j = 0; j < 8; j++) acc[i][j] = 0.f;

    int am = tid >> 1;            // 0..127
    int ak = (tid & 1) * 4;       // 0 or 4
    int bk = tid >> 5;            // 0..7
    int bn = (tid & 31) * 4;      // 0..124

    for (int k0 = 0; k0 < K; k0 += 8) {
        float4 av;
        if (m0 + am < M) av = *(const float4*)(A + (size_t)(m0 + am) * K + k0 + ak);
        else av = make_float4(0.f, 0.f, 0.f, 0.f);
        As[ak + 0][am] = av.x; As[ak + 1][am] = av.y;
        As[ak + 2][am] = av.z; As[ak + 3][am] = av.w;
        float4 bv;
        if (n0 + bn < N) bv = *(const float4*)(B + (size_t)(k0 + bk) * N + n0 + bn);
        else bv = make_float4(0.f, 0.f, 0.f, 0.f);
        *(float4*)&Bs[bk][bn] = bv;
        __syncthreads();
        #pragma unroll
        for (int k = 0; k < 8; k++) {
            float a[8], bb[8];
            *(float4*)&a[0]  = *(const float4*)&As[k][ty * 4];
            *(float4*)&a[4]  = *(const float4*)&As[k][ty * 4 + 64];
            *(float4*)&bb[0] = *(const float4*)&Bs[k][tx * 4];
            *(float4*)&bb[4] = *(const float4*)&Bs[k][tx * 4 + 64];
            #pragma unroll
            for (int i = 0; i < 8; i++)
                #pragma unroll
                for (int j = 0; j < 8; j++) acc[i][j] += a[i] * bb[j];
        }
        __syncthreads();
    }
    #pragma unroll
    for (int i = 0; i < 8; i++) {
        int m = m0 + ty * 4 + (i & 3) + (i >> 2) * 64;
        if (m >= M) continue;
        #pragma unroll
        for (int j = 0; j < 8; j++) {
            int n = n0 + tx * 4 + (j & 3) + (j >> 2) * 64;
            if (n < N) C[(size_t)m * N + n] = acc[i][j];
        }
    }
}

// ---------------- simple dot GEMM for small M ----------------
__global__ void k_dotgemm(const float* __restrict__ A, const float* __restrict__ B,
                          float* __restrict__ C, int M, int N, int K) {
    int i = blockIdx.x * 256 + threadIdx.x;
    if (i >= M * N) return;
    int m = i / N, n = i % N;
    const float* a = A + (size_t)m * K;
    const float* bp = B + n;
    float s = 0.f;
    for (int k = 0; k < K; k++) s += a[k] * bp[(size_t)k * N];
    C[i] = s;
}

// ---------------- dt / dA ----------------
__global__ void k_dt(const float* __restrict__ zx, const float* __restrict__ dtbias,
                     const float* __restrict__ Alog, float* __restrict__ dtb,
                     float* __restrict__ dAb) {
    int i = blockIdx.x * 256 + threadIdx.x;
    if (i >= ROWS * NHEADS) return;
    int h = i % NHEADS; int row = i / NHEADS;
    float x = zx[(size_t)row * D_IN_PROJ + D_INNER + CONV_DIM + h] + dtbias[h];
    float dt = (x > 20.f) ? x : log1pf(expf(x));
    dtb[i] = dt;
    dAb[i] = expf(-expf(Alog[h]) * dt);
}

// ---------------- depthwise causal conv + silu ----------------
__global__ void k_conv(const float* __restrict__ zx, const float* __restrict__ convw,
                       const float* __restrict__ convb, float* __restrict__ xBC) {
    int i = blockIdx.x * 256 + threadIdx.x;
    if (i >= ROWS * CONV_DIM) return;
    int c = i % CONV_DIM; int row = i / CONV_DIM;
    int l = row & 511; int b = row >> 9;
    float acc = convb[c];
    #pragma unroll
    for (int k = 0; k < 4; k++) {
        int t = l - 3 + k;
        if (t >= 0)
            acc += convw[c * 4 + k] * zx[(size_t)(b * SEQ + t) * D_IN_PROJ + D_INNER + c];
    }
    xBC[i] = siluf(acc);
}

// ---------------- sequential SSM scan: one block per (b, head) ----------------
__global__ __launch_bounds__(256)
void k_scan(const float* __restrict__ xBC, const float* __restrict__ dtb,
            const float* __restrict__ dAb, const float* __restrict__ Dssm,
            float* __restrict__ y) {
    int blk = blockIdx.x;
    int b = blk / NHEADS, h = blk % NHEADS;
    int tid = threadIdx.x;
    int p = tid >> 2, q = tid & 3;
    __shared__ float sBC[256];   // [0:128]=B, [128:256]=C
    float hst[32];
    #pragma unroll
    for (int j = 0; j < 32; j++) hst[j] = 0.f;
    float Dh = Dssm[h];
    for (int t = 0; t < SEQ; t++) {
        int row = b * SEQ + t;
        const float* xc = xBC + (size_t)row * CONV_DIM;
        sBC[tid] = xc[D_INNER + tid];    // tid 0..127 -> B, 128..255 -> C
        float dA  = dAb[row * NHEADS + h];
        float dtv = dtb[row * NHEADS + h];
        float xv  = xc[h * HEADDIM + p];
        __syncthreads();
        float dx = dtv * xv;
        float acc = 0.f;
        #pragma unroll
        for (int jj = 0; jj < 32; jj++) {
            int n = q * 32 + (jj ^ (q << 3));     // bank-stagger
            float hv = hst[jj] * dA + dx * sBC[n];
            hst[jj] = hv;
            acc += hv * sBC[128 + n];
        }
        acc += __shfl_xor(acc, 1, 64);
        acc += __shfl_xor(acc, 2, 64);
        if (q == 0) y[(size_t)row * D_INNER + h * HEADDIM + p] = acc + Dh * xv;
        __syncthreads();
    }
}

// ---------------- gated rmsnorm: rmsnorm(y * silu(z)) * w ----------------
__global__ void k_gatednorm(const float* __restrict__ yscan, const float* __restrict__ zx,
                            const float* __restrict__ nw, float* __restrict__ out) {
    __shared__ float s4[4];
    int row = blockIdx.x;
    const float* yp = yscan + (size_t)row * D_INNER;
    const float* zp = zx + (size_t)row * D_IN_PROJ;   // z at offset 0
    float v[6]; float ss = 0.f;
    #pragma unroll
    for (int j = 0; j < 6; j++) {
        int d = threadIdx.x + j * 256;
        float val = yp[d] * siluf(zp[d]);
        v[j] = val; ss += val * val;
    }
    ss = block_sum_256(ss, s4);
    float inv = rsqrtf(ss / (float)D_INNER + 1e-5f);
    #pragma unroll
    for (int j = 0; j < 6; j++) {
        int d = threadIdx.x + j * 256;
        out[(size_t)row * D_INNER + d] = v[j] * inv * nw[d];
    }
}

// ---------------- out = base + g * (raw + bias) ----------------
__global__ void k_fuse(const float* __restrict__ base, const float* __restrict__ raw,
                       const float* __restrict__ bias, const float* __restrict__ aff,
                       int goff, float* __restrict__ out) {
    int i = blockIdx.x * 256 + threadIdx.x;
    if (i >= ROWS * D_MODEL) return;
    int d = i % D_MODEL; int b = i / (SEQ * D_MODEL);
    float g = aff[b * 4608 + goff + d];
    out[i] = base[i] + g * (raw[i] + bias[d]);
}

// ---------------- ln_noaffine + mod ----------------
__global__ void k_lnmod(const float* __restrict__ hidden, const float* __restrict__ aff,
                        float* __restrict__ out) {
    __shared__ float s4[4];
    int row = blockIdx.x;
    int b = row >> 9;
    const float* hp = hidden + (size_t)row * D_MODEL;
    float v[3]; float s = 0.f;
    #pragma unroll
    for (int j = 0; j < 3; j++) { int d = threadIdx.x + j * 256; v[j] = hp[d]; s += v[j]; }
    float mean = block_sum_256(s, s4) / (float)D_MODEL;
    float ss = 0.f;
    #pragma unroll
    for (int j = 0; j < 3; j++) { float c = v[j] - mean; ss += c * c; }
    float var = block_sum_256(ss, s4) / (float)D_MODEL;
    float inv = rsqrtf(var + 1e-6f);
    const float* sh = aff + b * 4608 + 2304;  // sh_msa
    const float* sc = aff + b * 4608 + 3072;  // sc_msa
    #pragma unroll
    for (int j = 0; j < 3; j++) {
        int d = threadIdx.x + j * 256;
        float xh = (v[j] - mean) * inv;
        out[(size_t)row * D_MODEL + d] = xh * (1.f + sc[d]) + sh[d];
    }
}

// ---------------- cross-attention core ----------------
__global__ __launch_bounds__(64)
void k_attn(const float* __restrict__ q, const float* __restrict__ k,
            const float* __restrict__ v, float* __restrict__ o) {
    int blk = blockIdx.x;
    int l = blk & 511; int h = (blk >> 9) & 7; int b = blk >> 12;
    int m = threadIdx.x;
    const float* qp = q + ((size_t)(b * SEQ + l) * AH + h) * AD;
    const float* kp = k + ((size_t)(b * LC + m) * AH + h) * AD;
    float s = 0.f;
    #pragma unroll 8
    for (int d = 0; d < AD; d++) s += qp[d] * kp[d];
    s *= 0.125f;
    float mx = s;
    #pragma unroll
    for (int off = 32; off > 0; off >>= 1) mx = fmaxf(mx, __shfl_xor(mx, off, 64));
    float e = expf(s - mx);
    float sum = e;
    #pragma unroll
    for (int off = 32; off > 0; off >>= 1) sum += __shfl_xor(sum, off, 64);
    float a = e / sum;
    __shared__ float sa[64];
    sa[m] = a;
    __syncthreads();
    int d = threadIdx.x;
    float acc = 0.f;
    #pragma unroll 8
    for (int mm = 0; mm < LC; mm++)
        acc += sa[mm] * v[((size_t)(b * LC + mm) * AH + h) * AD + d];
    o[((size_t)(b * SEQ + l) * AH + h) * AD + d] = acc;
}

// ---------------- final rmsnorm(h + r) ----------------
__global__ void k_final(const float* __restrict__ hidden, const float* __restrict__ residual,
                        const float* __restrict__ w, float* __restrict__ out) {
    __shared__ float s4[4];
    int row = blockIdx.x;
    const float* hp = hidden + (size_t)row * D_MODEL;
    const float* rp = residual + (size_t)row * D_MODEL;
    float v[3]; float ss = 0.f;
    #pragma unroll
    for (int j = 0; j < 3; j++) {
        int d = threadIdx.x + j * 256;
        float x = hp[d] + rp[d];
        v[j] = x; ss += x * x;
    }
    ss = block_sum_256(ss, s4);
    float inv = rsqrtf(ss / (float)D_MODEL + 1e-5f);
    #pragma unroll
    for (int j = 0; j < 3; j++) {
        int d = threadIdx.x + j * 256;
        out[(size_t)row * D_MODEL + d] = v[j] * inv * w[d];
    }
}

// ---------------- host launch ----------------
extern "C" void kernel_launch(void* const* d_in, const int* in_sizes, int n_in,
                              void* d_out, int out_size, void* d_ws, size_t ws_size,
                              hipStream_t stream) {
    const float* hidden_states = (const float*)d_in[0];
    const float* ref_emb  = (const float*)d_in[1];
    const float* norm_w   = (const float*)d_in[2];
    const float* ada_w    = (const float*)d_in[3];
    const float* ada_b    = (const float*)d_in[4];
    const float* in_w     = (const float*)d_in[5];
    const float* conv_w   = (const float*)d_in[6];
    const float* conv_b   = (const float*)d_in[7];
    const float* dt_bias  = (const float*)d_in[8];
    const float* A_log    = (const float*)d_in[9];
    const float* D_ssm    = (const float*)d_in[10];
    const float* ssm_nw   = (const float*)d_in[11];
    const float* out_w    = (const float*)d_in[12];
    const float* out_b    = (const float*)d_in[13];
    const float* q_w      = (const float*)d_in[14];
    const float* k_w      = (const float*)d_in[15];
    const float* v_w      = (const float*)d_in[16];
    const float* o_w      = (const float*)d_in[17];
    const float* o_b      = (const float*)d_in[18];
    const float* norm_f_w = (const float*)d_in[19];
    float* out = (float*)d_out;

    float* ws = (float*)d_ws;
    float* residual = ws;                          ws += ROWS * D_MODEL;
    float* hidden   = ws;                          ws += ROWS * D_MODEL;
    float* hidden_n = ws;                          ws += ROWS * D_MODEL;
    float* u_mba    = ws;                          ws += ROWS * D_MODEL;
    float* zx       = ws;                          ws += (size_t)ROWS * D_IN_PROJ;
    float* xBC      = ws;                          ws += (size_t)ROWS * CONV_DIM;
    float* dtb      = ws;                          ws += ROWS * NHEADS;
    float* dAb      = ws;                          ws += ROWS * NHEADS;
    float* yscan    = ws;                          ws += (size_t)ROWS * D_INNER;
    float* ynorm    = ws;                          ws += (size_t)ROWS * D_INNER;
    float* tmp      = ws;                          ws += ROWS * D_MODEL;
    float* attnx    = ws;                          ws += ROWS * D_MODEL;
    float* qb       = ws;                          ws += ROWS * AINNER;
    float* kb       = ws;                          ws += BSZ * LC * AINNER;
    float* vb       = ws;                          ws += BSZ * LC * AINNER;
    float* ob       = ws;                          ws += ROWS * AINNER;
    float* aff      = ws;                          ws += BSZ * 4608;
    float* smc      = ws;                          ws += BSZ * D_MODEL;

    hipMemsetAsync(residual, 0, (size_t)ROWS * D_MODEL * sizeof(float), stream);
    k_silumean<<<(BSZ * D_MODEL + 255) / 256, 256, 0, stream>>>(ref_emb, smc);

    for (int layer = 0; layer < N_LAYER; layer++) {
        const float* L_norm_w  = norm_w  + layer * D_MODEL;
        const float* L_ada_w   = ada_w   + (size_t)layer * D_MODEL * 4608;
        const float* L_ada_b   = ada_b   + layer * 4608;
        const float* L_in_w    = in_w    + (size_t)layer * D_MODEL * D_IN_PROJ;
        const float* L_conv_w  = conv_w  + layer * CONV_DIM * 4;
        const float* L_conv_b  = conv_b  + layer * CONV_DIM;
        const float* L_dt_bias = dt_bias + layer * NHEADS;
        const float* L_A_log   = A_log   + layer * NHEADS;
        const float* L_D_ssm   = D_ssm   + layer * NHEADS;
        const float* L_ssm_nw  = ssm_nw  + layer * D_INNER;
        const float* L_out_w   = out_w   + (size_t)layer * D_INNER * D_MODEL;
        const float* L_out_b   = out_b   + layer * D_MODEL;
        const float* L_q_w     = q_w     + (size_t)layer * D_MODEL * AINNER;
        const float* L_k_w     = k_w     + (size_t)layer * D_MODEL * AINNER;
        const float* L_v_w     = v_w     + (size_t)layer * D_MODEL * AINNER;
        const float* L_o_w     = o_w     + (size_t)layer * AINNER * D_MODEL;
        const float* L_o_b     = o_b     + layer * D_MODEL;

        k_ada<<<(BSZ * 4608 + 255) / 256, 256, 0, stream>>>(smc, L_ada_w, L_ada_b, aff);
        k_addrmsmod<<<ROWS, 256, 0, stream>>>(layer == 0 ? hidden_states : hidden,
                                              residual, L_norm_w, aff, hidden_n, u_mba);
        k_sgemm<<<dim3(27, 8), 256, 0, stream>>>(u_mba, L_in_w, zx, ROWS, D_IN_PROJ, D_MODEL);
        k_dt<<<(ROWS * NHEADS + 255) / 256, 256, 0, stream>>>(zx, L_dt_bias, L_A_log, dtb, dAb);
        k_conv<<<(ROWS * CONV_DIM + 255) / 256, 256, 0, stream>>>(zx, L_conv_w, L_conv_b, xBC);
        k_scan<<<BSZ * NHEADS, 256, 0, stream>>>(xBC, dtb, dAb, L_D_ssm, yscan);
        k_gatednorm<<<ROWS, 256, 0, stream>>>(yscan, zx, L_ssm_nw, ynorm);
        k_sgemm<<<dim3(6, 8), 256, 0, stream>>>(ynorm, L_out_w, tmp, ROWS, D_MODEL, D_INNER);
        k_fuse<<<(ROWS * D_MODEL + 255) / 256, 256, 0, stream>>>(hidden_n, tmp, L_out_b, aff, 1536, hidden);
        k_lnmod<<<ROWS, 256, 0, stream>>>(hidden, aff, attnx);
        k_sgemm<<<dim3(4, 8), 256, 0, stream>>>(attnx, L_q_w, qb, ROWS, AINNER, D_MODEL);
        k_dotgemm<<<(BSZ * LC * AINNER + 255) / 256, 256, 0, stream>>>(ref_emb, L_k_w, kb, BSZ * LC, AINNER, D_MODEL);
        k_dotgemm<<<(BSZ * LC * AINNER + 255) / 256, 256, 0, stream>>>(ref_emb, L_v_w, vb, BSZ * LC, AINNER, D_MODEL);
        k_attn<<<BSZ * AH * SEQ, 64, 0, stream>>>(qb, kb, vb, ob);
        k_sgemm<<<dim3(6, 8), 256, 0, stream>>>(ob, L_o_w, tmp, ROWS, D_MODEL, AINNER);
        k_fuse<<<(ROWS * D_MODEL + 255) / 256, 256, 0, stream>>>(hidden, tmp, L_o_b, aff, 3840, hidden);
    }
    k_final<<<ROWS, 256, 0, stream>>>(hidden, residual, norm_f_w, out);
}

// Round 2
// 3391.159 us; speedup vs baseline: 4.2161x; 4.2161x over previous
//
#include <hip/hip_runtime.h>
#include <hip/hip_bf16.h>
#include <math.h>

// ---------------- constants ----------------
#define D_MODEL   768
#define N_LAYER   8
#define D_INNER   1536
#define D_STATE   128
#define HEADDIM   64
#define NHEADS    24
#define CONV_DIM  1792
#define D_IN_PROJ 3352
#define AH        8
#define AD        64
#define AINNER    512
#define BSZ       2
#define SEQ       512
#define LC        64
#define ROWS      (BSZ*SEQ)          // 1024
#define NCHUNK    8
#define CT        64                 // chunk length
#define NP1       3456               // 3352 padded to 27*128

typedef __attribute__((ext_vector_type(8))) short bf16x8;
typedef __attribute__((ext_vector_type(4))) float f32x4;

__device__ __forceinline__ float siluf(float x) { return x / (1.f + expf(-x)); }

__device__ __forceinline__ unsigned short f2b(float x) {
    __hip_bfloat16 h = __float2bfloat16(x);
    return __builtin_bit_cast(unsigned short, h);
}
__device__ __forceinline__ float b2f(unsigned short u) {
    unsigned v = ((unsigned)u) << 16;
    return __builtin_bit_cast(float, v);
}
__device__ __forceinline__ float4 b4(const unsigned short* p) {
    ushort4 u = *(const ushort4*)p;
    return make_float4(b2f(u.x), b2f(u.y), b2f(u.z), b2f(u.w));
}

// block-wide sum, 256 threads (4 waves)
__device__ __forceinline__ float block_sum_256(float v, float* s4) {
    #pragma unroll
    for (int o = 32; o > 0; o >>= 1) v += __shfl_down(v, o, 64);
    __syncthreads();
    if ((threadIdx.x & 63) == 0) s4[threadIdx.x >> 6] = v;
    __syncthreads();
    return s4[0] + s4[1] + s4[2] + s4[3];
}

// ---------------- fp32 -> bf16 elementwise ----------------
__global__ void k_f2b(const float* __restrict__ src, unsigned short* __restrict__ dst, int n) {
    int i = blockIdx.x * 256 + threadIdx.x;
    if (i < n) dst[i] = f2b(src[i]);
}

// ---------------- transpose+convert: src fp32 [K][N] -> dst bf16 [Npad][K], zero-pad n>=N ----
__global__ void k_transpose(const float* __restrict__ src, unsigned short* __restrict__ dst,
                            int K, int N) {
    __shared__ float tile[32][33];
    int n0 = blockIdx.x * 32, k0 = blockIdx.y * 32;
    int t = threadIdx.x;
    int nl = t & 31, kl = t >> 5;
    #pragma unroll
    for (int p = 0; p < 4; p++) {
        int k = kl + p * 8;
        int n = n0 + nl;
        tile[k][nl] = (n < N) ? src[(size_t)(k0 + k) * N + n] : 0.f;
    }
    __syncthreads();
    int kl2 = t & 31, nl2 = t >> 5;
    #pragma unroll
    for (int p = 0; p < 4; p++) {
        int n = nl2 + p * 8;
        dst[(size_t)(n0 + n) * K + k0 + kl2] = f2b(tile[kl2][n]);
    }
}

// ---------------- bf16 MFMA GEMM: C[M,N] = A[M,K] @ Bt[N,K]^T, C fp32 ----------------
// A bf16 [M][K] row-major, Bt bf16 [Npad][K] row-major (pre-transposed weights)
__global__ __launch_bounds__(256)
void k_gemm(const unsigned short* __restrict__ A, const unsigned short* __restrict__ Bt,
            float* __restrict__ C, int M, int N, int K) {
    __shared__ unsigned short As[128][40];
    __shared__ unsigned short Bs[128][40];
    int m0 = blockIdx.y * 128, n0 = blockIdx.x * 128;
    int tid = threadIdx.x;
    int lane = tid & 63, wave = tid >> 6;
    int wm = (wave >> 1) * 64, wn = (wave & 1) * 64;
    int l15 = lane & 15, quad = lane >> 4;
    f32x4 acc[4][4];
    #pragma unroll
    for (int i = 0; i < 4; i++)
        #pragma unroll
        for (int j = 0; j < 4; j++) acc[i][j] = (f32x4){0.f, 0.f, 0.f, 0.f};

    int srow = tid >> 2;            // 0..63
    int schunk = (tid & 3) * 8;     // 0,8,16,24  (halfs)

    for (int k0 = 0; k0 < K; k0 += 32) {
        #pragma unroll
        for (int ps = 0; ps < 2; ps++) {
            int r = srow + ps * 64;
            *(uint4*)&As[r][schunk] = *(const uint4*)&A[(size_t)(m0 + r) * K + k0 + schunk];
            *(uint4*)&Bs[r][schunk] = *(const uint4*)&Bt[(size_t)(n0 + r) * K + k0 + schunk];
        }
        __syncthreads();
        bf16x8 af[4], bfr[4];
        #pragma unroll
        for (int i = 0; i < 4; i++) af[i]  = *(const bf16x8*)&As[wm + i * 16 + l15][quad * 8];
        #pragma unroll
        for (int j = 0; j < 4; j++) bfr[j] = *(const bf16x8*)&Bs[wn + j * 16 + l15][quad * 8];
        #pragma unroll
        for (int i = 0; i < 4; i++)
            #pragma unroll
            for (int j = 0; j < 4; j++)
                acc[i][j] = __builtin_amdgcn_mfma_f32_16x16x32_bf16(af[i], bfr[j], acc[i][j], 0, 0, 0);
        __syncthreads();
    }
    #pragma unroll
    for (int i = 0; i < 4; i++) {
        #pragma unroll
        for (int j = 0; j < 4; j++) {
            int col = n0 + wn + j * 16 + l15;
            if (col < N) {
                #pragma unroll
                for (int r = 0; r < 4; r++) {
                    int row = m0 + wm + i * 16 + quad * 4 + r;
                    C[(size_t)row * N + col] = acc[i][j][r];
                }
            }
        }
    }
}

// ---------------- silu(mean(cond, axis=1)) ----------------
__global__ void k_silumean(const float* __restrict__ cond, float* __restrict__ smc) {
    int i = blockIdx.x * 256 + threadIdx.x;
    if (i >= BSZ * D_MODEL) return;
    int b = i / D_MODEL, d = i % D_MODEL;
    const float* p = cond + (size_t)b * LC * D_MODEL + d;
    float s = 0.f;
    #pragma unroll 4
    for (int l = 0; l < LC; l++) s += p[l * D_MODEL];
    s *= (1.f / (float)LC);
    smc[i] = siluf(s);
}

// ---------------- aff = smc @ ada_w + ada_b  (B x 4608) ----------------
__global__ void k_ada(const float* __restrict__ smc, const float* __restrict__ adaw,
                      const float* __restrict__ adab, float* __restrict__ aff) {
    int i = blockIdx.x * 256 + threadIdx.x;
    if (i >= BSZ * 4608) return;
    int b = i / 4608, j = i % 4608;
    const float* x = smc + b * D_MODEL;
    const float* w = adaw + j;
    float s = adab[j];
    for (int d = 0; d < D_MODEL; d++) s += x[d] * w[(size_t)d * 4608];
    aff[i] = s;
}

// ---------------- residual += hidden; rmsnorm; mod -> u (bf16) ----------------
__global__ void k_addrmsmod(const float* __restrict__ hin, float* __restrict__ residual,
                            const float* __restrict__ normw, const float* __restrict__ aff,
                            float* __restrict__ hidden_n, unsigned short* __restrict__ u) {
    __shared__ float s4[4];
    int row = blockIdx.x;
    int b = row >> 9;
    const float* hp = hin + (size_t)row * D_MODEL;
    float* rp = residual + (size_t)row * D_MODEL;
    float v[3]; float ss = 0.f;
    #pragma unroll
    for (int j = 0; j < 3; j++) {
        int d = threadIdx.x + j * 256;
        float x = hp[d] + rp[d];
        rp[d] = x; v[j] = x; ss += x * x;
    }
    ss = block_sum_256(ss, s4);
    float inv = rsqrtf(ss / (float)D_MODEL + 1e-5f);
    const float* sh = aff + b * 4608;
    const float* sc = aff + b * 4608 + 768;
    #pragma unroll
    for (int j = 0; j < 3; j++) {
        int d = threadIdx.x + j * 256;
        float hn = v[j] * inv * normw[d];
        hidden_n[(size_t)row * D_MODEL + d] = hn;
        u[(size_t)row * D_MODEL + d] = f2b(hn * (1.f + sc[d]) + sh[d]);
    }
}

// ---------------- dt = softplus ----------------
__global__ void k_dt(const float* __restrict__ zx, const float* __restrict__ dtbias,
                     float* __restrict__ dtb) {
    int i = blockIdx.x * 256 + threadIdx.x;
    if (i >= ROWS * NHEADS) return;
    int h = i % NHEADS; int row = i / NHEADS;
    float x = zx[(size_t)row * D_IN_PROJ + D_INNER + CONV_DIM + h] + dtbias[h];
    float dt = (x > 20.f) ? x : log1pf(expf(x));
    dtb[i] = dt;
}

// ---------------- depthwise causal conv + silu ----------------
__global__ void k_conv(const float* __restrict__ zx, const float* __restrict__ convw,
                       const float* __restrict__ convb, float* __restrict__ xBC) {
    int i = blockIdx.x * 256 + threadIdx.x;
    if (i >= ROWS * CONV_DIM) return;
    int c = i % CONV_DIM; int row = i / CONV_DIM;
    int l = row & 511; int b = row >> 9;
    float acc = convb[c];
    #pragma unroll
    for (int k = 0; k < 4; k++) {
        int t = l - 3 + k;
        if (t >= 0)
            acc += convw[c * 4 + k] * zx[(size_t)(b * SEQ + t) * D_IN_PROJ + D_INNER + c];
    }
    xBC[i] = siluf(acc);
}

// ---------------- S1: per-chunk end state ----------------
// block = (b*NHEADS+h)*NCHUNK + c ; 256 threads
__global__ __launch_bounds__(256)
void k_ssm_state(const float* __restrict__ xBC, const float* __restrict__ dtb,
                 const float* __restrict__ Alog, float* __restrict__ Sbuf,
                 float* __restrict__ Pbuf) {
    int blk = blockIdx.x;
    int c = blk & (NCHUNK - 1); int bh = blk >> 3;
    int h = bh % NHEADS; int b = bh / NHEADS;
    int tid = threadIdx.x;
    __shared__ float sB[64][132];
    __shared__ float sX[64][68];
    __shared__ float sL[64], sDt[64], sw[64];
    int base = b * SEQ + c * CT;
    int r = tid >> 2, q4 = tid & 3;
    const float* xrow = xBC + (size_t)(base + r) * CONV_DIM;
    #pragma unroll
    for (int j = 0; j < 8; j++)
        *(float4*)&sB[r][q4 * 32 + j * 4] = *(const float4*)&xrow[D_INNER + q4 * 32 + j * 4];
    #pragma unroll
    for (int j = 0; j < 4; j++)
        *(float4*)&sX[r][q4 * 16 + j * 4] = *(const float4*)&xrow[h * HEADDIM + q4 * 16 + j * 4];
    if (tid < 64) {
        float dt = dtb[(base + tid) * NHEADS + h];
        float a = expf(Alog[h]);
        float v = -a * dt;
        #pragma unroll
        for (int off = 1; off < 64; off <<= 1) {
            float u2 = __shfl_up(v, off, 64);
            if (tid >= off) v += u2;
        }
        sL[tid] = v; sDt[tid] = dt;
    }
    __syncthreads();
    if (tid < 64) sw[tid] = expf(sL[63] - sL[tid]) * sDt[tid];
    if (tid == 0) Pbuf[blk] = expf(sL[63]);
    __syncthreads();
    // S[p][n] = sum_t w_t * X[t][p] * B[t][n]; thread: p = tid>>2, n-range = (tid&3)*32..+32
    int p = tid >> 2, nb = (tid & 3) * 32;
    float acc[32];
    #pragma unroll
    for (int j = 0; j < 32; j++) acc[j] = 0.f;
    for (int t = 0; t < CT; t++) {
        float wx = sw[t] * sX[t][p];
        #pragma unroll
        for (int j0 = 0; j0 < 32; j0 += 4) {
            float4 bv = *(const float4*)&sB[t][nb + j0];
            acc[j0 + 0] += wx * bv.x; acc[j0 + 1] += wx * bv.y;
            acc[j0 + 2] += wx * bv.z; acc[j0 + 3] += wx * bv.w;
        }
    }
    size_t off = (size_t)blk * 8192 + p * 128 + nb;
    #pragma unroll
    for (int j0 = 0; j0 < 32; j0 += 4)
        *(float4*)&Sbuf[off + j0] = make_float4(acc[j0], acc[j0 + 1], acc[j0 + 2], acc[j0 + 3]);
}

// ---------------- S2: sequential chunk recurrence (parallel over state elems) ----------------
__global__ void k_ssm_seq(const float* __restrict__ Sbuf, const float* __restrict__ Pbuf,
                          unsigned short* __restrict__ hstart) {
    int bh = blockIdx.x >> 5; int part = blockIdx.x & 31;
    int idx = part * 256 + threadIdx.x;   // 0..8191
    float h = 0.f;
    #pragma unroll
    for (int c = 0; c < NCHUNK; c++) {
        size_t o = ((size_t)bh * NCHUNK + c) * 8192 + idx;
        hstart[o] = f2b(h);
        h = h * Pbuf[bh * NCHUNK + c] + Sbuf[o];
    }
}

// ---------------- S3: chunk outputs ----------------
__global__ __launch_bounds__(256)
void k_ssm_out(const float* __restrict__ xBC, const float* __restrict__ dtb,
               const float* __restrict__ Alog, const float* __restrict__ Dssm,
               const unsigned short* __restrict__ hstart, float* __restrict__ y) {
    int blk = blockIdx.x;
    int c = blk & (NCHUNK - 1); int bh = blk >> 3;
    int h = bh % NHEADS; int b = bh / NHEADS;
    int tid = threadIdx.x;
    __shared__ unsigned short sB[64][136];   // later aliased to hstart tile
    __shared__ unsigned short sC[64][136];
    __shared__ unsigned short sX[64][72];
    __shared__ float sG[64][65];
    __shared__ float sL[64], sDt[64];
    int base = b * SEQ + c * CT;
    int r = tid >> 2, q4 = tid & 3;
    const float* xrow = xBC + (size_t)(base + r) * CONV_DIM;
    #pragma unroll
    for (int j = 0; j < 8; j++) {
        float4 v = *(const float4*)&xrow[D_INNER + q4 * 32 + j * 4];
        int cc = q4 * 32 + j * 4;
        sB[r][cc + 0] = f2b(v.x); sB[r][cc + 1] = f2b(v.y);
        sB[r][cc + 2] = f2b(v.z); sB[r][cc + 3] = f2b(v.w);
        float4 w = *(const float4*)&xrow[D_INNER + D_STATE + q4 * 32 + j * 4];
        sC[r][cc + 0] = f2b(w.x); sC[r][cc + 1] = f2b(w.y);
        sC[r][cc + 2] = f2b(w.z); sC[r][cc + 3] = f2b(w.w);
    }
    #pragma unroll
    for (int j = 0; j < 4; j++) {
        float4 v = *(const float4*)&xrow[h * HEADDIM + q4 * 16 + j * 4];
        int cc = q4 * 16 + j * 4;
        sX[r][cc + 0] = f2b(v.x); sX[r][cc + 1] = f2b(v.y);
        sX[r][cc + 2] = f2b(v.z); sX[r][cc + 3] = f2b(v.w);
    }
    if (tid < 64) {
        float dt = dtb[(base + tid) * NHEADS + h];
        float a = expf(Alog[h]);
        float v = -a * dt;
        #pragma unroll
        for (int off = 1; off < 64; off <<= 1) {
            float u2 = __shfl_up(v, off, 64);
            if (tid >= off) v += u2;
        }
        sL[tid] = v; sDt[tid] = dt;
    }
    __syncthreads();
    // G[i][s] = (C_i . B_s) * exp(L_i - L_s) * dt_s for s<=i else 0
    {
        int i = tid >> 2, j0 = (tid & 3) * 16;
        float g[16];
        #pragma unroll
        for (int jj = 0; jj < 16; jj++) g[jj] = 0.f;
        for (int k0 = 0; k0 < D_STATE; k0 += 4) {
            float4 cv = b4(&sC[i][k0]);
            #pragma unroll
            for (int jj = 0; jj < 16; jj++) {
                float4 bv = b4(&sB[j0 + jj][k0]);
                g[jj] += cv.x * bv.x + cv.y * bv.y + cv.z * bv.z + cv.w * bv.w;
            }
        }
        float Li = sL[i];
        #pragma unroll
        for (int jj = 0; jj < 16; jj++) {
            int s = j0 + jj;
            sG[i][s] = (s <= i) ? g[jj] * expf(Li - sL[s]) * sDt[s] : 0.f;
        }
    }
    __syncthreads();
    // overwrite sB with hstart tile (bf16 [p][n])
    {
        const unsigned short* hsrc = hstart + ((size_t)bh * NCHUNK + c) * 8192;
        #pragma unroll
        for (int j = 0; j < 4; j++)
            *(uint4*)&sB[r][q4 * 32 + j * 8] = *(const uint4*)&hsrc[r * 128 + q4 * 32 + j * 8];
    }
    __syncthreads();
    {
        int i = tid >> 2, p0 = (tid & 3) * 16;
        float acc[16];
        #pragma unroll
        for (int pp = 0; pp < 16; pp++) acc[pp] = 0.f;
        // intra: sum_s G[i][s] * X[s][p]
        for (int s = 0; s <= i; s++) {
            float g = sG[i][s];
            #pragma unroll
            for (int pp = 0; pp < 16; pp += 4) {
                float4 xv = b4(&sX[s][p0 + pp]);
                acc[pp + 0] += g * xv.x; acc[pp + 1] += g * xv.y;
                acc[pp + 2] += g * xv.z; acc[pp + 3] += g * xv.w;
            }
        }
        // inter: exp(L_i) * sum_n C[i][n] * hstart[p][n]
        float hacc[16];
        #pragma unroll
        for (int pp = 0; pp < 16; pp++) hacc[pp] = 0.f;
        for (int n0 = 0; n0 < D_STATE; n0 += 4) {
            float4 cv = b4(&sC[i][n0]);
            #pragma unroll
            for (int pp = 0; pp < 16; pp++) {
                float4 hv = b4(&sB[p0 + pp][n0]);
                hacc[pp] += cv.x * hv.x + cv.y * hv.y + cv.z * hv.z + cv.w * hv.w;
            }
        }
        float el = expf(sL[i]);
        float Dh = Dssm[h];
        float* yrow = y + (size_t)(base + i) * D_INNER + h * HEADDIM;
        #pragma unroll
        for (int pp = 0; pp < 16; pp++) {
            float xv = b2f(sX[i][p0 + pp]);
            yrow[p0 + pp] = acc[pp] + el * hacc[pp] + Dh * xv;
        }
    }
}

// ---------------- gated rmsnorm -> bf16 ----------------
__global__ void k_gatednorm(const float* __restrict__ yscan, const float* __restrict__ zx,
                            const float* __restrict__ nw, unsigned short* __restrict__ out) {
    __shared__ float s4[4];
    int row = blockIdx.x;
    const float* yp = yscan + (size_t)row * D_INNER;
    const float* zp = zx + (size_t)row * D_IN_PROJ;
    float v[6]; float ss = 0.f;
    #pragma unroll
    for (int j = 0; j < 6; j++) {
        int d = threadIdx.x + j * 256;
        float val = yp[d] * siluf(zp[d]);
        v[j] = val; ss += val * val;
    }
    ss = block_sum_256(ss, s4);
    float inv = rsqrtf(ss / (float)D_INNER + 1e-5f);
    #pragma unroll
    for (int j = 0; j < 6; j++) {
        int d = threadIdx.x + j * 256;
        out[(size_t)row * D_INNER + d] = f2b(v[j] * inv * nw[d]);
    }
}

// ---------------- out = base + g * (raw + bias) ----------------
__global__ void k_fuse(const float* __restrict__ base, const float* __restrict__ raw,
                       const float* __restrict__ bias, const float* __restrict__ aff,
                       int goff, float* __restrict__ out) {
    int i = blockIdx.x * 256 + threadIdx.x;
    if (i >= ROWS * D_MODEL) return;
    int d = i % D_MODEL; int b = i / (SEQ * D_MODEL);
    float g = aff[b * 4608 + goff + d];
    out[i] = base[i] + g * (raw[i] + bias[d]);
}

// ---------------- ln_noaffine + mod -> bf16 ----------------
__global__ void k_lnmod(const float* __restrict__ hidden, const float* __restrict__ aff,
                        unsigned short* __restrict__ out) {
    __shared__ float s4[4];
    int row = blockIdx.x;
    int b = row >> 9;
    const float* hp = hidden + (size_t)row * D_MODEL;
    float v[3]; float s = 0.f;
    #pragma unroll
    for (int j = 0; j < 3; j++) { int d = threadIdx.x + j * 256; v[j] = hp[d]; s += v[j]; }
    float mean = block_sum_256(s, s4) / (float)D_MODEL;
    float ss = 0.f;
    #pragma unroll
    for (int j = 0; j < 3; j++) { float cdel = v[j] - mean; ss += cdel * cdel; }
    float var = block_sum_256(ss, s4) / (float)D_MODEL;
    float inv = rsqrtf(var + 1e-6f);
    const float* sh = aff + b * 4608 + 2304;
    const float* sc = aff + b * 4608 + 3072;
    #pragma unroll
    for (int j = 0; j < 3; j++) {
        int d = threadIdx.x + j * 256;
        float xh = (v[j] - mean) * inv;
        out[(size_t)row * D_MODEL + d] = f2b(xh * (1.f + sc[d]) + sh[d]);
    }
}

// ---------------- cross-attention core -> ob bf16 ----------------
__global__ __launch_bounds__(64)
void k_attn(const float* __restrict__ q, const float* __restrict__ k,
            const float* __restrict__ v, unsigned short* __restrict__ o) {
    int blk = blockIdx.x;
    int l = blk & 511; int h = (blk >> 9) & 7; int b = blk >> 12;
    int m = threadIdx.x;
    const float* qp = q + ((size_t)(b * SEQ + l) * AH + h) * AD;
    const float* kp = k + ((size_t)(b * LC + m) * AH + h) * AD;
    float s = 0.f;
    #pragma unroll 8
    for (int d = 0; d < AD; d++) s += qp[d] * kp[d];
    s *= 0.125f;
    float mx = s;
    #pragma unroll
    for (int off = 32; off > 0; off >>= 1) mx = fmaxf(mx, __shfl_xor(mx, off, 64));
    float e = expf(s - mx);
    float sum = e;
    #pragma unroll
    for (int off = 32; off > 0; off >>= 1) sum += __shfl_xor(sum, off, 64);
    float a = e / sum;
    __shared__ float sa[64];
    sa[m] = a;
    __syncthreads();
    int d = threadIdx.x;
    float acc = 0.f;
    #pragma unroll 8
    for (int mm = 0; mm < LC; mm++)
        acc += sa[mm] * v[((size_t)(b * LC + mm) * AH + h) * AD + d];
    o[((size_t)(b * SEQ + l) * AH + h) * AD + d] = f2b(acc);
}

// ---------------- final rmsnorm(h + r) ----------------
__global__ void k_final(const float* __restrict__ hidden, const float* __restrict__ residual,
                        const float* __restrict__ w, float* __restrict__ out) {
    __shared__ float s4[4];
    int row = blockIdx.x;
    const float* hp = hidden + (size_t)row * D_MODEL;
    const float* rp = residual + (size_t)row * D_MODEL;
    float v[3]; float ss = 0.f;
    #pragma unroll
    for (int j = 0; j < 3; j++) {
        int d = threadIdx.x + j * 256;
        float x = hp[d] + rp[d];
        v[j] = x; ss += x * x;
    }
    ss = block_sum_256(ss, s4);
    float inv = rsqrtf(ss / (float)D_MODEL + 1e-5f);
    #pragma unroll
    for (int j = 0; j < 3; j++) {
        int d = threadIdx.x + j * 256;
        out[(size_t)row * D_MODEL + d] = v[j] * inv * w[d];
    }
}

// ---------------- host launch ----------------
extern "C" void kernel_launch(void* const* d_in, const int* in_sizes, int n_in,
                              void* d_out, int out_size, void* d_ws, size_t ws_size,
                              hipStream_t stream) {
    const float* hidden_states = (const float*)d_in[0];
    const float* ref_emb  = (const float*)d_in[1];
    const float* norm_w   = (const float*)d_in[2];
    const float* ada_w    = (const float*)d_in[3];
    const float* ada_b    = (const float*)d_in[4];
    const float* in_w     = (const float*)d_in[5];
    const float* conv_w   = (const float*)d_in[6];
    const float* conv_b   = (const float*)d_in[7];
    const float* dt_bias  = (const float*)d_in[8];
    const float* A_log    = (const float*)d_in[9];
    const float* D_ssm    = (const float*)d_in[10];
    const float* ssm_nw   = (const float*)d_in[11];
    const float* out_w    = (const float*)d_in[12];
    const float* out_b    = (const float*)d_in[13];
    const float* q_w      = (const float*)d_in[14];
    const float* k_w      = (const float*)d_in[15];
    const float* v_w      = (const float*)d_in[16];
    const float* o_w      = (const float*)d_in[17];
    const float* o_b      = (const float*)d_in[18];
    const float* norm_f_w = (const float*)d_in[19];
    float* out = (float*)d_out;

    char* p = (char*)d_ws;
    auto alloc = [&](size_t bytes) -> char* {
        char* r = p; p += (bytes + 255) & ~(size_t)255; return r;
    };
    float* residual = (float*)alloc((size_t)ROWS * D_MODEL * 4);
    float* hidden   = (float*)alloc((size_t)ROWS * D_MODEL * 4);
    float* hidden_n = (float*)alloc((size_t)ROWS * D_MODEL * 4);
    float* tmp      = (float*)alloc((size_t)ROWS * D_MODEL * 4);
    float* zx       = (float*)alloc((size_t)ROWS * D_IN_PROJ * 4);
    float* xBC      = (float*)alloc((size_t)ROWS * CONV_DIM * 4);
    float* dtb      = (float*)alloc((size_t)ROWS * NHEADS * 4);
    float* yscan    = (float*)alloc((size_t)ROWS * D_INNER * 4);
    float* qb       = (float*)alloc((size_t)ROWS * AINNER * 4);
    float* kb       = (float*)alloc((size_t)BSZ * LC * AINNER * 4);
    float* vb       = (float*)alloc((size_t)BSZ * LC * AINNER * 4);
    float* aff      = (float*)alloc((size_t)BSZ * 4608 * 4);
    float* smc      = (float*)alloc((size_t)BSZ * D_MODEL * 4);
    float* Sbuf     = (float*)alloc((size_t)BSZ * NHEADS * NCHUNK * 8192 * 4);
    float* Pbuf     = (float*)alloc((size_t)BSZ * NHEADS * NCHUNK * 4);
    unsigned short* hstart = (unsigned short*)alloc((size_t)BSZ * NHEADS * NCHUNK * 8192 * 2);
    unsigned short* u_bf   = (unsigned short*)alloc((size_t)ROWS * D_MODEL * 2);
    unsigned short* ynorm  = (unsigned short*)alloc((size_t)ROWS * D_INNER * 2);
    unsigned short* attnx  = (unsigned short*)alloc((size_t)ROWS * D_MODEL * 2);
    unsigned short* ob     = (unsigned short*)alloc((size_t)ROWS * AINNER * 2);
    unsigned short* ref_bf = (unsigned short*)alloc((size_t)BSZ * LC * D_MODEL * 2);
    unsigned short* in_wt  = (unsigned short*)alloc((size_t)NP1 * D_MODEL * 2);
    unsigned short* out_wt = (unsigned short*)alloc((size_t)D_MODEL * D_INNER * 2);
    unsigned short* q_wt   = (unsigned short*)alloc((size_t)AINNER * D_MODEL * 2);
    unsigned short* k_wt   = (unsigned short*)alloc((size_t)AINNER * D_MODEL * 2);
    unsigned short* v_wt   = (unsigned short*)alloc((size_t)AINNER * D_MODEL * 2);
    unsigned short* o_wt   = (unsigned short*)alloc((size_t)D_MODEL * AINNER * 2);

    hipMemsetAsync(residual, 0, (size_t)ROWS * D_MODEL * sizeof(float), stream);
    k_silumean<<<(BSZ * D_MODEL + 255) / 256, 256, 0, stream>>>(ref_emb, smc);
    k_f2b<<<(BSZ * LC * D_MODEL + 255) / 256, 256, 0, stream>>>(ref_emb, ref_bf, BSZ * LC * D_MODEL);

    for (int layer = 0; layer < N_LAYER; layer++) {
        const float* L_norm_w  = norm_w  + layer * D_MODEL;
        const float* L_ada_w   = ada_w   + (size_t)layer * D_MODEL * 4608;
        const float* L_ada_b   = ada_b   + layer * 4608;
        const float* L_in_w    = in_w    + (size_t)layer * D_MODEL * D_IN_PROJ;
        const float* L_conv_w  = conv_w  + layer * CONV_DIM * 4;
        const float* L_conv_b  = conv_b  + layer * CONV_DIM;
        const float* L_dt_bias = dt_bias + layer * NHEADS;
        const float* L_A_log   = A_log   + layer * NHEADS;
        const float* L_D_ssm   = D_ssm   + layer * NHEADS;
        const float* L_ssm_nw  = ssm_nw  + layer * D_INNER;
        const float* L_out_w   = out_w   + (size_t)layer * D_INNER * D_MODEL;
        const float* L_out_b   = out_b   + layer * D_MODEL;
        const float* L_q_w     = q_w     + (size_t)layer * D_MODEL * AINNER;
        const float* L_k_w     = k_w     + (size_t)layer * D_MODEL * AINNER;
        const float* L_v_w     = v_w     + (size_t)layer * D_MODEL * AINNER;
        const float* L_o_w     = o_w     + (size_t)layer * AINNER * D_MODEL;
        const float* L_o_b     = o_b     + layer * D_MODEL;

        // weight transposes (fp32 [K][N] -> bf16 [Npad][K])
        k_transpose<<<dim3(NP1 / 32, D_MODEL / 32), 256, 0, stream>>>(L_in_w, in_wt, D_MODEL, D_IN_PROJ);
        k_transpose<<<dim3(D_MODEL / 32, D_INNER / 32), 256, 0, stream>>>(L_out_w, out_wt, D_INNER, D_MODEL);
        k_transpose<<<dim3(AINNER / 32, D_MODEL / 32), 256, 0, stream>>>(L_q_w, q_wt, D_MODEL, AINNER);
        k_transpose<<<dim3(AINNER / 32, D_MODEL / 32), 256, 0, stream>>>(L_k_w, k_wt, D_MODEL, AINNER);
        k_transpose<<<dim3(AINNER / 32, D_MODEL / 32), 256, 0, stream>>>(L_v_w, v_wt, D_MODEL, AINNER);
        k_transpose<<<dim3(D_MODEL / 32, AINNER / 32), 256, 0, stream>>>(L_o_w, o_wt, AINNER, D_MODEL);

        k_ada<<<(BSZ * 4608 + 255) / 256, 256, 0, stream>>>(smc, L_ada_w, L_ada_b, aff);
        k_addrmsmod<<<ROWS, 256, 0, stream>>>(layer == 0 ? hidden_states : hidden,
                                              residual, L_norm_w, aff, hidden_n, u_bf);
        k_gemm<<<dim3(NP1 / 128, ROWS / 128), 256, 0, stream>>>(u_bf, in_wt, zx, ROWS, D_IN_PROJ, D_MODEL);
        k_dt<<<(ROWS * NHEADS + 255) / 256, 256, 0, stream>>>(zx, L_dt_bias, dtb);
        k_conv<<<(ROWS * CONV_DIM + 255) / 256, 256, 0, stream>>>(zx, L_conv_w, L_conv_b, xBC);
        k_ssm_state<<<BSZ * NHEADS * NCHUNK, 256, 0, stream>>>(xBC, dtb, L_A_log, Sbuf, Pbuf);
        k_ssm_seq<<<BSZ * NHEADS * 32, 256, 0, stream>>>(Sbuf, Pbuf, hstart);
        k_ssm_out<<<BSZ * NHEADS * NCHUNK, 256, 0, stream>>>(xBC, dtb, L_A_log, L_D_ssm, hstart, yscan);
        k_gatednorm<<<ROWS, 256, 0, stream>>>(yscan, zx, L_ssm_nw, ynorm);
        k_gemm<<<dim3(D_MODEL / 128, ROWS / 128), 256, 0, stream>>>(ynorm, out_wt, tmp, ROWS, D_MODEL, D_INNER);
        k_fuse<<<(ROWS * D_MODEL + 255) / 256, 256, 0, stream>>>(hidden_n, tmp, L_out_b, aff, 1536, hidden);
        k_lnmod<<<ROWS, 256, 0, stream>>>(hidden, aff, attnx);
        k_gemm<<<dim3(AINNER / 128, ROWS / 128), 256, 0, stream>>>(attnx, q_wt, qb, ROWS, AINNER, D_MODEL);
        k_gemm<<<dim3(AINNER / 128, 1), 256, 0, stream>>>(ref_bf, k_wt, kb, BSZ * LC, AINNER, D_MODEL);
        k_gemm<<<dim3(AINNER / 128, 1), 256, 0, stream>>>(ref_bf, v_wt, vb, BSZ * LC, AINNER, D_MODEL);
        k_attn<<<BSZ * AH * SEQ, 64, 0, stream>>>(qb, kb, vb, ob);
        k_gemm<<<dim3(D_MODEL / 128, ROWS / 128), 256, 0, stream>>>(ob, o_wt, tmp, ROWS, D_MODEL, AINNER);
        k_fuse<<<(ROWS * D_MODEL + 255) / 256, 256, 0, stream>>>(hidden, tmp, L_o_b, aff, 3840, hidden);
    }
    k_final<<<ROWS, 256, 0, stream>>>(hidden, residual, norm_f_w, out);
}

// Round 3
// 2420.136 us; speedup vs baseline: 5.9077x; 1.4012x over previous
//
#include <hip/hip_runtime.h>
#include <hip/hip_bf16.h>
#include <math.h>

// ---------------- constants ----------------
#define D_MODEL   768
#define N_LAYER   8
#define D_INNER   1536
#define D_STATE   128
#define HEADDIM   64
#define NHEADS    24
#define CONV_DIM  1792
#define D_IN_PROJ 3352
#define AH        8
#define AD        64
#define AINNER    512
#define BSZ       2
#define SEQ       512
#define LC        64
#define ROWS      (BSZ*SEQ)          // 1024
#define NCHUNK    8
#define CT        64                 // chunk length
#define NP1       3456               // 3352 padded to 27*128
#define AFF       4608

typedef __attribute__((ext_vector_type(8))) short bf16x8;
typedef __attribute__((ext_vector_type(4))) float f32x4;

__device__ __forceinline__ float siluf(float x) { return x / (1.f + expf(-x)); }

__device__ __forceinline__ unsigned short f2b(float x) {
    __hip_bfloat16 h = __float2bfloat16(x);
    return __builtin_bit_cast(unsigned short, h);
}
__device__ __forceinline__ float b2f(unsigned short u) {
    unsigned v = ((unsigned)u) << 16;
    return __builtin_bit_cast(float, v);
}
__device__ __forceinline__ float4 b4(const unsigned short* p) {
    ushort4 u = *(const ushort4*)p;
    return make_float4(b2f(u.x), b2f(u.y), b2f(u.z), b2f(u.w));
}

// block-wide sum, 256 threads (4 waves)
__device__ __forceinline__ float block_sum_256(float v, float* s4) {
    #pragma unroll
    for (int o = 32; o > 0; o >>= 1) v += __shfl_down(v, o, 64);
    __syncthreads();
    if ((threadIdx.x & 63) == 0) s4[threadIdx.x >> 6] = v;
    __syncthreads();
    return s4[0] + s4[1] + s4[2] + s4[3];
}

// ---------------- fp32 -> bf16 elementwise ----------------
__global__ void k_f2b(const float* __restrict__ src, unsigned short* __restrict__ dst, int n) {
    int i = blockIdx.x * 256 + threadIdx.x;
    if (i < n) dst[i] = f2b(src[i]);
}

// ---------------- transpose+convert: src fp32 [K][N] -> dst bf16 [Npad][K] ----------------
__global__ void k_transpose(const float* __restrict__ src, unsigned short* __restrict__ dst,
                            int K, int N) {
    __shared__ float tile[32][33];
    int n0 = blockIdx.x * 32, k0 = blockIdx.y * 32;
    int t = threadIdx.x;
    int nl = t & 31, kl = t >> 5;
    #pragma unroll
    for (int p = 0; p < 4; p++) {
        int k = kl + p * 8;
        int n = n0 + nl;
        tile[k][nl] = (n < N) ? src[(size_t)(k0 + k) * N + n] : 0.f;
    }
    __syncthreads();
    int kl2 = t & 31, nl2 = t >> 5;
    #pragma unroll
    for (int p = 0; p < 4; p++) {
        int n = nl2 + p * 8;
        dst[(size_t)(n0 + n) * K + k0 + kl2] = f2b(tile[kl2][n]);
    }
}

// batched over layers (z): no padding (K,N multiples of 32)
__global__ void k_transpose_b(const float* __restrict__ src, unsigned short* __restrict__ dst,
                              int K, int N) {
    int z = blockIdx.z;
    src += (size_t)z * K * N;
    dst += (size_t)z * N * K;
    __shared__ float tile[32][33];
    int n0 = blockIdx.x * 32, k0 = blockIdx.y * 32;
    int t = threadIdx.x;
    int nl = t & 31, kl = t >> 5;
    #pragma unroll
    for (int p = 0; p < 4; p++)
        tile[kl + p * 8][nl] = src[(size_t)(k0 + kl + p * 8) * N + n0 + nl];
    __syncthreads();
    int kl2 = t & 31, nl2 = t >> 5;
    #pragma unroll
    for (int p = 0; p < 4; p++) {
        int n = nl2 + p * 8;
        dst[(size_t)(n0 + n) * K + k0 + kl2] = f2b(tile[kl2][n]);
    }
}

// ---------------- bf16 MFMA GEMM: C[M,N] = A[M,K] @ Bt[N,K]^T, C fp32 ----------------
__global__ __launch_bounds__(256)
void k_gemm(const unsigned short* __restrict__ A, const unsigned short* __restrict__ Bt,
            float* __restrict__ C, int M, int N, int K) {
    __shared__ unsigned short As[128][40];
    __shared__ unsigned short Bs[128][40];
    int m0 = blockIdx.y * 128, n0 = blockIdx.x * 128;
    int tid = threadIdx.x;
    int lane = tid & 63, wave = tid >> 6;
    int wm = (wave >> 1) * 64, wn = (wave & 1) * 64;
    int l15 = lane & 15, quad = lane >> 4;
    f32x4 acc[4][4];
    #pragma unroll
    for (int i = 0; i < 4; i++)
        #pragma unroll
        for (int j = 0; j < 4; j++) acc[i][j] = (f32x4){0.f, 0.f, 0.f, 0.f};

    int srow = tid >> 2;
    int schunk = (tid & 3) * 8;

    for (int k0 = 0; k0 < K; k0 += 32) {
        #pragma unroll
        for (int ps = 0; ps < 2; ps++) {
            int r = srow + ps * 64;
            *(uint4*)&As[r][schunk] = *(const uint4*)&A[(size_t)(m0 + r) * K + k0 + schunk];
            *(uint4*)&Bs[r][schunk] = *(const uint4*)&Bt[(size_t)(n0 + r) * K + k0 + schunk];
        }
        __syncthreads();
        bf16x8 af[4], bfr[4];
        #pragma unroll
        for (int i = 0; i < 4; i++) af[i]  = *(const bf16x8*)&As[wm + i * 16 + l15][quad * 8];
        #pragma unroll
        for (int j = 0; j < 4; j++) bfr[j] = *(const bf16x8*)&Bs[wn + j * 16 + l15][quad * 8];
        #pragma unroll
        for (int i = 0; i < 4; i++)
            #pragma unroll
            for (int j = 0; j < 4; j++)
                acc[i][j] = __builtin_amdgcn_mfma_f32_16x16x32_bf16(af[i], bfr[j], acc[i][j], 0, 0, 0);
        __syncthreads();
    }
    #pragma unroll
    for (int i = 0; i < 4; i++) {
        #pragma unroll
        for (int j = 0; j < 4; j++) {
            int col = n0 + wn + j * 16 + l15;
            if (col < N) {
                #pragma unroll
                for (int r = 0; r < 4; r++) {
                    int row = m0 + wm + i * 16 + quad * 4 + r;
                    C[(size_t)row * N + col] = acc[i][j][r];
                }
            }
        }
    }
}

// batched K/V projection: A = ref_bf [128][768]; z -> (layer, k-or-v)
__global__ __launch_bounds__(256)
void k_gemm_kv(const unsigned short* __restrict__ A, const unsigned short* __restrict__ Kwt,
               const unsigned short* __restrict__ Vwt, float* __restrict__ Kb,
               float* __restrict__ Vb) {
    int z = blockIdx.z; int layer = z >> 1; int which = z & 1;
    const unsigned short* Bt = (which ? Vwt : Kwt) + (size_t)layer * AINNER * D_MODEL;
    float* C = (which ? Vb : Kb) + (size_t)layer * (BSZ * LC) * AINNER;
    __shared__ unsigned short As[128][40];
    __shared__ unsigned short Bs[128][40];
    int n0 = blockIdx.x * 128;
    int tid = threadIdx.x;
    int lane = tid & 63, wave = tid >> 6;
    int wm = (wave >> 1) * 64, wn = (wave & 1) * 64;
    int l15 = lane & 15, quad = lane >> 4;
    f32x4 acc[4][4];
    #pragma unroll
    for (int i = 0; i < 4; i++)
        #pragma unroll
        for (int j = 0; j < 4; j++) acc[i][j] = (f32x4){0.f, 0.f, 0.f, 0.f};
    int srow = tid >> 2, schunk = (tid & 3) * 8;
    for (int k0 = 0; k0 < D_MODEL; k0 += 32) {
        #pragma unroll
        for (int ps = 0; ps < 2; ps++) {
            int r = srow + ps * 64;
            *(uint4*)&As[r][schunk] = *(const uint4*)&A[(size_t)r * D_MODEL + k0 + schunk];
            *(uint4*)&Bs[r][schunk] = *(const uint4*)&Bt[(size_t)(n0 + r) * D_MODEL + k0 + schunk];
        }
        __syncthreads();
        bf16x8 af[4], bfr[4];
        #pragma unroll
        for (int i = 0; i < 4; i++) af[i]  = *(const bf16x8*)&As[wm + i * 16 + l15][quad * 8];
        #pragma unroll
        for (int j = 0; j < 4; j++) bfr[j] = *(const bf16x8*)&Bs[wn + j * 16 + l15][quad * 8];
        #pragma unroll
        for (int i = 0; i < 4; i++)
            #pragma unroll
            for (int j = 0; j < 4; j++)
                acc[i][j] = __builtin_amdgcn_mfma_f32_16x16x32_bf16(af[i], bfr[j], acc[i][j], 0, 0, 0);
        __syncthreads();
    }
    #pragma unroll
    for (int i = 0; i < 2; i++) {        // only rows < 128 exist; wm+i*16+... < 128 always (wm<=64,i<4) — keep 4
        ;
    }
    #pragma unroll
    for (int i = 0; i < 4; i++) {
        #pragma unroll
        for (int j = 0; j < 4; j++) {
            int col = n0 + wn + j * 16 + l15;
            #pragma unroll
            for (int r = 0; r < 4; r++) {
                int row = wm + i * 16 + quad * 4 + r;
                C[(size_t)row * AINNER + col] = acc[i][j][r];
            }
        }
    }
}

// ---------------- silu(mean(cond, axis=1)) ----------------
__global__ void k_silumean(const float* __restrict__ cond, float* __restrict__ smc) {
    int i = blockIdx.x * 256 + threadIdx.x;
    if (i >= BSZ * D_MODEL) return;
    int b = i / D_MODEL, d = i % D_MODEL;
    const float* p = cond + (size_t)b * LC * D_MODEL + d;
    float s = 0.f;
    #pragma unroll 4
    for (int l = 0; l < LC; l++) s += p[l * D_MODEL];
    s *= (1.f / (float)LC);
    smc[i] = siluf(s);
}

// ---------------- aff_all init with bias ----------------
__global__ void k_ada_init(const float* __restrict__ adab, float* __restrict__ aff_all) {
    int i = blockIdx.x * 256 + threadIdx.x;
    if (i >= N_LAYER * BSZ * AFF) return;
    int j = i % AFF; int lb = i / AFF; int l = lb >> 1;
    aff_all[i] = adab[l * AFF + j];
}

// ---------------- split-K ada: aff_all[l][b][j] += sum_d smc[b][d]*w[l][d][j] ----------------
__global__ void k_ada_split(const float* __restrict__ smc, const float* __restrict__ adaw,
                            float* __restrict__ aff_all) {
    int l = blockIdx.z;
    int kc = blockIdx.y;          // 0..7 -> d range [kc*96, kc*96+96)
    int j = blockIdx.x * 256 + threadIdx.x;   // 0..4607
    const float* w = adaw + (size_t)l * D_MODEL * AFF + j;
    const float* x0 = smc;
    const float* x1 = smc + D_MODEL;
    float s0 = 0.f, s1 = 0.f;
    int d0 = kc * 96;
    #pragma unroll 8
    for (int d = d0; d < d0 + 96; d++) {
        float wv = w[(size_t)d * AFF];
        s0 += x0[d] * wv; s1 += x1[d] * wv;
    }
    atomicAdd(&aff_all[(size_t)l * BSZ * AFF + j], s0);
    atomicAdd(&aff_all[(size_t)l * BSZ * AFF + AFF + j], s1);
}

// ---------------- [fused prev-attn out] + residual update + rmsnorm + mod ----------------
__global__ void k_addrmsmod(const float* __restrict__ hin, const float* __restrict__ raw,
                            const float* __restrict__ bias, const float* __restrict__ affprev,
                            float* __restrict__ residual, const float* __restrict__ normw,
                            const float* __restrict__ affcur,
                            float* __restrict__ hidden_n, unsigned short* __restrict__ u,
                            int has_raw) {
    __shared__ float s4[4];
    int row = blockIdx.x;
    int b = row >> 9;
    const float* hp = hin + (size_t)row * D_MODEL;
    float* rp = residual + (size_t)row * D_MODEL;
    float v[3]; float ss = 0.f;
    #pragma unroll
    for (int j = 0; j < 3; j++) {
        int d = threadIdx.x + j * 256;
        float x = hp[d];
        if (has_raw) {
            float g = affprev[b * AFF + 3840 + d];
            x += g * (raw[(size_t)row * D_MODEL + d] + bias[d]);
        }
        x += rp[d];
        rp[d] = x; v[j] = x; ss += x * x;
    }
    ss = block_sum_256(ss, s4);
    float inv = rsqrtf(ss / (float)D_MODEL + 1e-5f);
    const float* sh = affcur + b * AFF;
    const float* sc = affcur + b * AFF + 768;
    #pragma unroll
    for (int j = 0; j < 3; j++) {
        int d = threadIdx.x + j * 256;
        float hn = v[j] * inv * normw[d];
        hidden_n[(size_t)row * D_MODEL + d] = hn;
        u[(size_t)row * D_MODEL + d] = f2b(hn * (1.f + sc[d]) + sh[d]);
    }
}

// ---------------- depthwise causal conv + silu, fused softplus(dt) ----------------
__global__ void k_convdt(const float* __restrict__ zx, const float* __restrict__ convw,
                         const float* __restrict__ convb, const float* __restrict__ dtbias,
                         float* __restrict__ xBC, float* __restrict__ dtb) {
    int i = blockIdx.x * 256 + threadIdx.x;
    if (i < ROWS * NHEADS) {
        int h = i % NHEADS; int row = i / NHEADS;
        float x = zx[(size_t)row * D_IN_PROJ + D_INNER + CONV_DIM + h] + dtbias[h];
        dtb[i] = (x > 20.f) ? x : log1pf(expf(x));
    }
    if (i >= ROWS * CONV_DIM) return;
    int c = i % CONV_DIM; int row = i / CONV_DIM;
    int l = row & 511; int b = row >> 9;
    float acc = convb[c];
    #pragma unroll
    for (int k = 0; k < 4; k++) {
        int t = l - 3 + k;
        if (t >= 0)
            acc += convw[c * 4 + k] * zx[(size_t)(b * SEQ + t) * D_IN_PROJ + D_INNER + c];
    }
    xBC[i] = siluf(acc);
}

// ---------------- S1: per-chunk end state ----------------
__global__ __launch_bounds__(256)
void k_ssm_state(const float* __restrict__ xBC, const float* __restrict__ dtb,
                 const float* __restrict__ Alog, float* __restrict__ Sbuf,
                 float* __restrict__ Pbuf) {
    int blk = blockIdx.x;
    int c = blk & (NCHUNK - 1); int bh = blk >> 3;
    int h = bh % NHEADS; int b = bh / NHEADS;
    int tid = threadIdx.x;
    __shared__ float sB[64][132];
    __shared__ float sX[64][68];
    __shared__ float sL[64], sDt[64], sw[64];
    int base = b * SEQ + c * CT;
    int r = tid >> 2, q4 = tid & 3;
    const float* xrow = xBC + (size_t)(base + r) * CONV_DIM;
    #pragma unroll
    for (int j = 0; j < 8; j++)
        *(float4*)&sB[r][q4 * 32 + j * 4] = *(const float4*)&xrow[D_INNER + q4 * 32 + j * 4];
    #pragma unroll
    for (int j = 0; j < 4; j++)
        *(float4*)&sX[r][q4 * 16 + j * 4] = *(const float4*)&xrow[h * HEADDIM + q4 * 16 + j * 4];
    if (tid < 64) {
        float dt = dtb[(base + tid) * NHEADS + h];
        float a = expf(Alog[h]);
        float v = -a * dt;
        #pragma unroll
        for (int off = 1; off < 64; off <<= 1) {
            float u2 = __shfl_up(v, off, 64);
            if (tid >= off) v += u2;
        }
        sL[tid] = v; sDt[tid] = dt;
    }
    __syncthreads();
    if (tid < 64) sw[tid] = expf(sL[63] - sL[tid]) * sDt[tid];
    if (tid == 0) Pbuf[blk] = expf(sL[63]);
    __syncthreads();
    int p = tid >> 2, nb = (tid & 3) * 32;
    float acc[32];
    #pragma unroll
    for (int j = 0; j < 32; j++) acc[j] = 0.f;
    for (int t = 0; t < CT; t++) {
        float wx = sw[t] * sX[t][p];
        #pragma unroll
        for (int j0 = 0; j0 < 32; j0 += 4) {
            float4 bv = *(const float4*)&sB[t][nb + j0];
            acc[j0 + 0] += wx * bv.x; acc[j0 + 1] += wx * bv.y;
            acc[j0 + 2] += wx * bv.z; acc[j0 + 3] += wx * bv.w;
        }
    }
    size_t off = (size_t)blk * 8192 + p * 128 + nb;
    #pragma unroll
    for (int j0 = 0; j0 < 32; j0 += 4)
        *(float4*)&Sbuf[off + j0] = make_float4(acc[j0], acc[j0 + 1], acc[j0 + 2], acc[j0 + 3]);
}

// ---------------- S2: sequential chunk recurrence ----------------
__global__ void k_ssm_seq(const float* __restrict__ Sbuf, const float* __restrict__ Pbuf,
                          unsigned short* __restrict__ hstart) {
    int bh = blockIdx.x >> 5; int part = blockIdx.x & 31;
    int idx = part * 256 + threadIdx.x;
    float h = 0.f;
    #pragma unroll
    for (int c = 0; c < NCHUNK; c++) {
        size_t o = ((size_t)bh * NCHUNK + c) * 8192 + idx;
        hstart[o] = f2b(h);
        h = h * Pbuf[bh * NCHUNK + c] + Sbuf[o];
    }
}

// ---------------- S3: chunk outputs ----------------
__global__ __launch_bounds__(256)
void k_ssm_out(const float* __restrict__ xBC, const float* __restrict__ dtb,
               const float* __restrict__ Alog, const float* __restrict__ Dssm,
               const unsigned short* __restrict__ hstart, float* __restrict__ y) {
    int blk = blockIdx.x;
    int c = blk & (NCHUNK - 1); int bh = blk >> 3;
    int h = bh % NHEADS; int b = bh / NHEADS;
    int tid = threadIdx.x;
    __shared__ unsigned short sB[64][136];
    __shared__ unsigned short sC[64][136];
    __shared__ unsigned short sX[64][72];
    __shared__ float sG[64][65];
    __shared__ float sL[64], sDt[64];
    int base = b * SEQ + c * CT;
    int r = tid >> 2, q4 = tid & 3;
    const float* xrow = xBC + (size_t)(base + r) * CONV_DIM;
    #pragma unroll
    for (int j = 0; j < 8; j++) {
        float4 v = *(const float4*)&xrow[D_INNER + q4 * 32 + j * 4];
        int cc = q4 * 32 + j * 4;
        sB[r][cc + 0] = f2b(v.x); sB[r][cc + 1] = f2b(v.y);
        sB[r][cc + 2] = f2b(v.z); sB[r][cc + 3] = f2b(v.w);
        float4 w = *(const float4*)&xrow[D_INNER + D_STATE + q4 * 32 + j * 4];
        sC[r][cc + 0] = f2b(w.x); sC[r][cc + 1] = f2b(w.y);
        sC[r][cc + 2] = f2b(w.z); sC[r][cc + 3] = f2b(w.w);
    }
    #pragma unroll
    for (int j = 0; j < 4; j++) {
        float4 v = *(const float4*)&xrow[h * HEADDIM + q4 * 16 + j * 4];
        int cc = q4 * 16 + j * 4;
        sX[r][cc + 0] = f2b(v.x); sX[r][cc + 1] = f2b(v.y);
        sX[r][cc + 2] = f2b(v.z); sX[r][cc + 3] = f2b(v.w);
    }
    if (tid < 64) {
        float dt = dtb[(base + tid) * NHEADS + h];
        float a = expf(Alog[h]);
        float v = -a * dt;
        #pragma unroll
        for (int off = 1; off < 64; off <<= 1) {
            float u2 = __shfl_up(v, off, 64);
            if (tid >= off) v += u2;
        }
        sL[tid] = v; sDt[tid] = dt;
    }
    __syncthreads();
    {
        int i = tid >> 2, j0 = (tid & 3) * 16;
        float g[16];
        #pragma unroll
        for (int jj = 0; jj < 16; jj++) g[jj] = 0.f;
        for (int k0 = 0; k0 < D_STATE; k0 += 4) {
            float4 cv = b4(&sC[i][k0]);
            #pragma unroll
            for (int jj = 0; jj < 16; jj++) {
                float4 bv = b4(&sB[j0 + jj][k0]);
                g[jj] += cv.x * bv.x + cv.y * bv.y + cv.z * bv.z + cv.w * bv.w;
            }
        }
        float Li = sL[i];
        #pragma unroll
        for (int jj = 0; jj < 16; jj++) {
            int s = j0 + jj;
            sG[i][s] = (s <= i) ? g[jj] * expf(Li - sL[s]) * sDt[s] : 0.f;
        }
    }
    __syncthreads();
    {
        const unsigned short* hsrc = hstart + ((size_t)bh * NCHUNK + c) * 8192;
        #pragma unroll
        for (int j = 0; j < 4; j++)
            *(uint4*)&sB[r][q4 * 32 + j * 8] = *(const uint4*)&hsrc[r * 128 + q4 * 32 + j * 8];
    }
    __syncthreads();
    {
        int i = tid >> 2, p0 = (tid & 3) * 16;
        float acc[16];
        #pragma unroll
        for (int pp = 0; pp < 16; pp++) acc[pp] = 0.f;
        for (int s = 0; s <= i; s++) {
            float g = sG[i][s];
            #pragma unroll
            for (int pp = 0; pp < 16; pp += 4) {
                float4 xv = b4(&sX[s][p0 + pp]);
                acc[pp + 0] += g * xv.x; acc[pp + 1] += g * xv.y;
                acc[pp + 2] += g * xv.z; acc[pp + 3] += g * xv.w;
            }
        }
        float hacc[16];
        #pragma unroll
        for (int pp = 0; pp < 16; pp++) hacc[pp] = 0.f;
        for (int n0 = 0; n0 < D_STATE; n0 += 4) {
            float4 cv = b4(&sC[i][n0]);
            #pragma unroll
            for (int pp = 0; pp < 16; pp++) {
                float4 hv = b4(&sB[p0 + pp][n0]);
                hacc[pp] += cv.x * hv.x + cv.y * hv.y + cv.z * hv.z + cv.w * hv.w;
            }
        }
        float el = expf(sL[i]);
        float Dh = Dssm[h];
        float* yrow = y + (size_t)(base + i) * D_INNER + h * HEADDIM;
        #pragma unroll
        for (int pp = 0; pp < 16; pp++) {
            float xv = b2f(sX[i][p0 + pp]);
            yrow[p0 + pp] = acc[pp] + el * hacc[pp] + Dh * xv;
        }
    }
}

// ---------------- gated rmsnorm -> bf16 ----------------
__global__ void k_gatednorm(const float* __restrict__ yscan, const float* __restrict__ zx,
                            const float* __restrict__ nw, unsigned short* __restrict__ out) {
    __shared__ float s4[4];
    int row = blockIdx.x;
    const float* yp = yscan + (size_t)row * D_INNER;
    const float* zp = zx + (size_t)row * D_IN_PROJ;
    float v[6]; float ss = 0.f;
    #pragma unroll
    for (int j = 0; j < 6; j++) {
        int d = threadIdx.x + j * 256;
        float val = yp[d] * siluf(zp[d]);
        v[j] = val; ss += val * val;
    }
    ss = block_sum_256(ss, s4);
    float inv = rsqrtf(ss / (float)D_INNER + 1e-5f);
    #pragma unroll
    for (int j = 0; j < 6; j++) {
        int d = threadIdx.x + j * 256;
        out[(size_t)row * D_INNER + d] = f2b(v[j] * inv * nw[d]);
    }
}

// ---------------- hidden2 = hidden_n + g_mba*(tmp+out_b); ln_noaffine + msa mod -> bf16 ----
__global__ void k_fuse_ln(const float* __restrict__ hidden_n, const float* __restrict__ tmp,
                          const float* __restrict__ outb, const float* __restrict__ aff,
                          float* __restrict__ hidden2, unsigned short* __restrict__ attnx) {
    __shared__ float s4[4];
    int row = blockIdx.x;
    int b = row >> 9;
    const float* gm = aff + b * AFF + 1536;
    float v[3]; float s = 0.f;
    #pragma unroll
    for (int j = 0; j < 3; j++) {
        int d = threadIdx.x + j * 256;
        float x = hidden_n[(size_t)row * D_MODEL + d]
                + gm[d] * (tmp[(size_t)row * D_MODEL + d] + outb[d]);
        hidden2[(size_t)row * D_MODEL + d] = x;
        v[j] = x; s += x;
    }
    float mean = block_sum_256(s, s4) / (float)D_MODEL;
    float ss = 0.f;
    #pragma unroll
    for (int j = 0; j < 3; j++) { float c = v[j] - mean; ss += c * c; }
    float var = block_sum_256(ss, s4) / (float)D_MODEL;
    float inv = rsqrtf(var + 1e-6f);
    const float* sh = aff + b * AFF + 2304;
    const float* sc = aff + b * AFF + 3072;
    #pragma unroll
    for (int j = 0; j < 3; j++) {
        int d = threadIdx.x + j * 256;
        float xh = (v[j] - mean) * inv;
        attnx[(size_t)row * D_MODEL + d] = f2b(xh * (1.f + sc[d]) + sh[d]);
    }
}

// ---------------- cross-attention core -> ob bf16 ----------------
__global__ __launch_bounds__(64)
void k_attn(const float* __restrict__ q, const float* __restrict__ k,
            const float* __restrict__ v, unsigned short* __restrict__ o) {
    int blk = blockIdx.x;
    int l = blk & 511; int h = (blk >> 9) & 7; int b = blk >> 12;
    int m = threadIdx.x;
    const float* qp = q + ((size_t)(b * SEQ + l) * AH + h) * AD;
    const float* kp = k + ((size_t)(b * LC + m) * AH + h) * AD;
    float s = 0.f;
    #pragma unroll 8
    for (int d = 0; d < AD; d++) s += qp[d] * kp[d];
    s *= 0.125f;
    float mx = s;
    #pragma unroll
    for (int off = 32; off > 0; off >>= 1) mx = fmaxf(mx, __shfl_xor(mx, off, 64));
    float e = expf(s - mx);
    float sum = e;
    #pragma unroll
    for (int off = 32; off > 0; off >>= 1) sum += __shfl_xor(sum, off, 64);
    float a = e / sum;
    __shared__ float sa[64];
    sa[m] = a;
    __syncthreads();
    int d = threadIdx.x;
    float acc = 0.f;
    #pragma unroll 8
    for (int mm = 0; mm < LC; mm++)
        acc += sa[mm] * v[((size_t)(b * LC + mm) * AH + h) * AD + d];
    o[((size_t)(b * SEQ + l) * AH + h) * AD + d] = f2b(acc);
}

// ---------------- final: h = hidden2 + g*(raw+bias); rmsnorm(h + r) ----------------
__global__ void k_final(const float* __restrict__ hidden2, const float* __restrict__ raw,
                        const float* __restrict__ bias, const float* __restrict__ aff,
                        const float* __restrict__ residual, const float* __restrict__ w,
                        float* __restrict__ out) {
    __shared__ float s4[4];
    int row = blockIdx.x;
    int b = row >> 9;
    const float* gm = aff + b * AFF + 3840;
    float v[3]; float ss = 0.f;
    #pragma unroll
    for (int j = 0; j < 3; j++) {
        int d = threadIdx.x + j * 256;
        float x = hidden2[(size_t)row * D_MODEL + d]
                + gm[d] * (raw[(size_t)row * D_MODEL + d] + bias[d])
                + residual[(size_t)row * D_MODEL + d];
        v[j] = x; ss += x * x;
    }
    ss = block_sum_256(ss, s4);
    float inv = rsqrtf(ss / (float)D_MODEL + 1e-5f);
    #pragma unroll
    for (int j = 0; j < 3; j++) {
        int d = threadIdx.x + j * 256;
        out[(size_t)row * D_MODEL + d] = v[j] * inv * w[d];
    }
}

// ---------------- host launch ----------------
extern "C" void kernel_launch(void* const* d_in, const int* in_sizes, int n_in,
                              void* d_out, int out_size, void* d_ws, size_t ws_size,
                              hipStream_t stream) {
    const float* hidden_states = (const float*)d_in[0];
    const float* ref_emb  = (const float*)d_in[1];
    const float* norm_w   = (const float*)d_in[2];
    const float* ada_w    = (const float*)d_in[3];
    const float* ada_b    = (const float*)d_in[4];
    const float* in_w     = (const float*)d_in[5];
    const float* conv_w   = (const float*)d_in[6];
    const float* conv_b   = (const float*)d_in[7];
    const float* dt_bias  = (const float*)d_in[8];
    const float* A_log    = (const float*)d_in[9];
    const float* D_ssm    = (const float*)d_in[10];
    const float* ssm_nw   = (const float*)d_in[11];
    const float* out_w    = (const float*)d_in[12];
    const float* out_b    = (const float*)d_in[13];
    const float* q_w      = (const float*)d_in[14];
    const float* k_w      = (const float*)d_in[15];
    const float* v_w      = (const float*)d_in[16];
    const float* o_w      = (const float*)d_in[17];
    const float* o_b      = (const float*)d_in[18];
    const float* norm_f_w = (const float*)d_in[19];
    float* out = (float*)d_out;

    char* p = (char*)d_ws;
    auto alloc = [&](size_t bytes) -> char* {
        char* r = p; p += (bytes + 255) & ~(size_t)255; return r;
    };
    float* residual = (float*)alloc((size_t)ROWS * D_MODEL * 4);
    float* hidden2  = (float*)alloc((size_t)ROWS * D_MODEL * 4);
    float* hidden_n = (float*)alloc((size_t)ROWS * D_MODEL * 4);
    float* tmp      = (float*)alloc((size_t)ROWS * D_MODEL * 4);
    float* zx       = (float*)alloc((size_t)ROWS * D_IN_PROJ * 4);
    float* xBC      = (float*)alloc((size_t)ROWS * CONV_DIM * 4);
    float* dtb      = (float*)alloc((size_t)ROWS * NHEADS * 4);
    float* yscan    = (float*)alloc((size_t)ROWS * D_INNER * 4);
    float* qb       = (float*)alloc((size_t)ROWS * AINNER * 4);
    float* kb_all   = (float*)alloc((size_t)N_LAYER * BSZ * LC * AINNER * 4);
    float* vb_all   = (float*)alloc((size_t)N_LAYER * BSZ * LC * AINNER * 4);
    float* aff_all  = (float*)alloc((size_t)N_LAYER * BSZ * AFF * 4);
    float* smc      = (float*)alloc((size_t)BSZ * D_MODEL * 4);
    float* Sbuf     = (float*)alloc((size_t)BSZ * NHEADS * NCHUNK * 8192 * 4);
    float* Pbuf     = (float*)alloc((size_t)BSZ * NHEADS * NCHUNK * 4);
    unsigned short* hstart = (unsigned short*)alloc((size_t)BSZ * NHEADS * NCHUNK * 8192 * 2);
    unsigned short* u_bf   = (unsigned short*)alloc((size_t)ROWS * D_MODEL * 2);
    unsigned short* ynorm  = (unsigned short*)alloc((size_t)ROWS * D_INNER * 2);
    unsigned short* attnx  = (unsigned short*)alloc((size_t)ROWS * D_MODEL * 2);
    unsigned short* ob     = (unsigned short*)alloc((size_t)ROWS * AINNER * 2);
    unsigned short* ref_bf = (unsigned short*)alloc((size_t)BSZ * LC * D_MODEL * 2);
    unsigned short* in_wt  = (unsigned short*)alloc((size_t)NP1 * D_MODEL * 2);
    unsigned short* out_wt = (unsigned short*)alloc((size_t)D_MODEL * D_INNER * 2);
    unsigned short* q_wt   = (unsigned short*)alloc((size_t)AINNER * D_MODEL * 2);
    unsigned short* o_wt   = (unsigned short*)alloc((size_t)D_MODEL * AINNER * 2);
    unsigned short* kwt_all = (unsigned short*)alloc((size_t)N_LAYER * AINNER * D_MODEL * 2);
    unsigned short* vwt_all = (unsigned short*)alloc((size_t)N_LAYER * AINNER * D_MODEL * 2);

    hipMemsetAsync(residual, 0, (size_t)ROWS * D_MODEL * sizeof(float), stream);
    k_silumean<<<(BSZ * D_MODEL + 255) / 256, 256, 0, stream>>>(ref_emb, smc);
    k_f2b<<<(BSZ * LC * D_MODEL + 255) / 256, 256, 0, stream>>>(ref_emb, ref_bf, BSZ * LC * D_MODEL);
    // aff for all layers
    k_ada_init<<<(N_LAYER * BSZ * AFF + 255) / 256, 256, 0, stream>>>(ada_b, aff_all);
    k_ada_split<<<dim3(AFF / 256, 8, N_LAYER), 256, 0, stream>>>(smc, ada_w, aff_all);
    // k/v for all layers
    k_transpose_b<<<dim3(AINNER / 32, D_MODEL / 32, N_LAYER), 256, 0, stream>>>(k_w, kwt_all, D_MODEL, AINNER);
    k_transpose_b<<<dim3(AINNER / 32, D_MODEL / 32, N_LAYER), 256, 0, stream>>>(v_w, vwt_all, D_MODEL, AINNER);
    k_gemm_kv<<<dim3(AINNER / 128, 1, N_LAYER * 2), 256, 0, stream>>>(ref_bf, kwt_all, vwt_all, kb_all, vb_all);

    for (int layer = 0; layer < N_LAYER; layer++) {
        const float* L_norm_w  = norm_w  + layer * D_MODEL;
        const float* L_in_w    = in_w    + (size_t)layer * D_MODEL * D_IN_PROJ;
        const float* L_conv_w  = conv_w  + layer * CONV_DIM * 4;
        const float* L_conv_b  = conv_b  + layer * CONV_DIM;
        const float* L_dt_bias = dt_bias + layer * NHEADS;
        const float* L_A_log   = A_log   + layer * NHEADS;
        const float* L_D_ssm   = D_ssm   + layer * NHEADS;
        const float* L_ssm_nw  = ssm_nw  + layer * D_INNER;
        const float* L_out_w   = out_w   + (size_t)layer * D_INNER * D_MODEL;
        const float* L_out_b   = out_b   + layer * D_MODEL;
        const float* L_q_w     = q_w     + (size_t)layer * D_MODEL * AINNER;
        const float* L_o_w     = o_w     + (size_t)layer * AINNER * D_MODEL;
        const float* L_o_b_prev= o_b     + (layer - 1) * D_MODEL;
        const float* L_aff     = aff_all + (size_t)layer * BSZ * AFF;
        const float* L_aff_prev= aff_all + (size_t)(layer - 1) * BSZ * AFF;

        k_transpose<<<dim3(NP1 / 32, D_MODEL / 32), 256, 0, stream>>>(L_in_w, in_wt, D_MODEL, D_IN_PROJ);
        k_transpose<<<dim3(D_MODEL / 32, D_INNER / 32), 256, 0, stream>>>(L_out_w, out_wt, D_INNER, D_MODEL);
        k_transpose<<<dim3(AINNER / 32, D_MODEL / 32), 256, 0, stream>>>(L_q_w, q_wt, D_MODEL, AINNER);
        k_transpose<<<dim3(D_MODEL / 32, AINNER / 32), 256, 0, stream>>>(L_o_w, o_wt, AINNER, D_MODEL);

        k_addrmsmod<<<ROWS, 256, 0, stream>>>(
            layer == 0 ? hidden_states : hidden2, tmp,
            layer == 0 ? o_b : L_o_b_prev,
            layer == 0 ? aff_all : L_aff_prev,
            residual, L_norm_w, L_aff, hidden_n, u_bf, layer == 0 ? 0 : 1);
        k_gemm<<<dim3(NP1 / 128, ROWS / 128), 256, 0, stream>>>(u_bf, in_wt, zx, ROWS, D_IN_PROJ, D_MODEL);
        k_convdt<<<(ROWS * CONV_DIM + 255) / 256, 256, 0, stream>>>(zx, L_conv_w, L_conv_b, L_dt_bias, xBC, dtb);
        k_ssm_state<<<BSZ * NHEADS * NCHUNK, 256, 0, stream>>>(xBC, dtb, L_A_log, Sbuf, Pbuf);
        k_ssm_seq<<<BSZ * NHEADS * 32, 256, 0, stream>>>(Sbuf, Pbuf, hstart);
        k_ssm_out<<<BSZ * NHEADS * NCHUNK, 256, 0, stream>>>(xBC, dtb, L_A_log, L_D_ssm, hstart, yscan);
        k_gatednorm<<<ROWS, 256, 0, stream>>>(yscan, zx, L_ssm_nw, ynorm);
        k_gemm<<<dim3(D_MODEL / 128, ROWS / 128), 256, 0, stream>>>(ynorm, out_wt, tmp, ROWS, D_MODEL, D_INNER);
        k_fuse_ln<<<ROWS, 256, 0, stream>>>(hidden_n, tmp, L_out_b, L_aff, hidden2, attnx);
        k_gemm<<<dim3(AINNER / 128, ROWS / 128), 256, 0, stream>>>(attnx, q_wt, qb, ROWS, AINNER, D_MODEL);
        k_attn<<<BSZ * AH * SEQ, 64, 0, stream>>>(
            qb, kb_all + (size_t)layer * BSZ * LC * AINNER,
            vb_all + (size_t)layer * BSZ * LC * AINNER, ob);
        k_gemm<<<dim3(D_MODEL / 128, ROWS / 128), 256, 0, stream>>>(ob, o_wt, tmp, ROWS, D_MODEL, AINNER);
    }
    k_final<<<ROWS, 256, 0, stream>>>(hidden2, tmp, o_b + (N_LAYER - 1) * D_MODEL,
                                      aff_all + (size_t)(N_LAYER - 1) * BSZ * AFF,
                                      residual, norm_f_w, out);
}

// Round 4
// 1865.754 us; speedup vs baseline: 7.6631x; 1.2971x over previous
//
#include <hip/hip_runtime.h>
#include <hip/hip_bf16.h>
#include <math.h>

// ---------------- constants ----------------
#define D_MODEL   768
#define N_LAYER   8
#define D_INNER   1536
#define D_STATE   128
#define HEADDIM   64
#define NHEADS    24
#define CONV_DIM  1792
#define D_IN_PROJ 3352
#define AH        8
#define AD        64
#define AINNER    512
#define BSZ       2
#define SEQ       512
#define LC        64
#define ROWS      (BSZ*SEQ)          // 1024
#define NCHUNK    8
#define CT        64                 // chunk length
#define NP1       3456               // 3352 padded to 27*128
#define AFF       4608

typedef __attribute__((ext_vector_type(8))) short bf16x8;
typedef __attribute__((ext_vector_type(4))) float f32x4;

__device__ __forceinline__ float siluf(float x) { return x / (1.f + expf(-x)); }

__device__ __forceinline__ unsigned short f2b(float x) {
    __hip_bfloat16 h = __float2bfloat16(x);
    return __builtin_bit_cast(unsigned short, h);
}
__device__ __forceinline__ float b2f(unsigned short u) {
    unsigned v = ((unsigned)u) << 16;
    return __builtin_bit_cast(float, v);
}

// block-wide sum, 256 threads (4 waves)
__device__ __forceinline__ float block_sum_256(float v, float* s4) {
    #pragma unroll
    for (int o = 32; o > 0; o >>= 1) v += __shfl_down(v, o, 64);
    __syncthreads();
    if ((threadIdx.x & 63) == 0) s4[threadIdx.x >> 6] = v;
    __syncthreads();
    return s4[0] + s4[1] + s4[2] + s4[3];
}

// ---------------- fp32 -> bf16 elementwise ----------------
__global__ void k_f2b(const float* __restrict__ src, unsigned short* __restrict__ dst, int n) {
    int i = blockIdx.x * 256 + threadIdx.x;
    if (i < n) dst[i] = f2b(src[i]);
}

// ---------------- transpose+convert: src fp32 [K][N] -> dst bf16 [Npad][K] ----------------
__global__ void k_transpose(const float* __restrict__ src, unsigned short* __restrict__ dst,
                            int K, int N) {
    __shared__ float tile[32][33];
    int n0 = blockIdx.x * 32, k0 = blockIdx.y * 32;
    int t = threadIdx.x;
    int nl = t & 31, kl = t >> 5;
    #pragma unroll
    for (int p = 0; p < 4; p++) {
        int k = kl + p * 8;
        int n = n0 + nl;
        tile[k][nl] = (n < N) ? src[(size_t)(k0 + k) * N + n] : 0.f;
    }
    __syncthreads();
    int kl2 = t & 31, nl2 = t >> 5;
    #pragma unroll
    for (int p = 0; p < 4; p++) {
        int n = nl2 + p * 8;
        dst[(size_t)(n0 + n) * K + k0 + kl2] = f2b(tile[kl2][n]);
    }
}

// batched over layers (z)
__global__ void k_transpose_b(const float* __restrict__ src, unsigned short* __restrict__ dst,
                              int K, int N) {
    int z = blockIdx.z;
    src += (size_t)z * K * N;
    dst += (size_t)z * N * K;
    __shared__ float tile[32][33];
    int n0 = blockIdx.x * 32, k0 = blockIdx.y * 32;
    int t = threadIdx.x;
    int nl = t & 31, kl = t >> 5;
    #pragma unroll
    for (int p = 0; p < 4; p++)
        tile[kl + p * 8][nl] = src[(size_t)(k0 + kl + p * 8) * N + n0 + nl];
    __syncthreads();
    int kl2 = t & 31, nl2 = t >> 5;
    #pragma unroll
    for (int p = 0; p < 4; p++) {
        int n = nl2 + p * 8;
        dst[(size_t)(n0 + n) * K + k0 + kl2] = f2b(tile[kl2][n]);
    }
}

// ---------------- bf16 MFMA GEMM: C[M,N] = A[M,K] @ Bt[N,K]^T, C fp32 ----------------
__global__ __launch_bounds__(256)
void k_gemm(const unsigned short* __restrict__ A, const unsigned short* __restrict__ Bt,
            float* __restrict__ C, int M, int N, int K) {
    __shared__ unsigned short As[128][40];
    __shared__ unsigned short Bs[128][40];
    int m0 = blockIdx.y * 128, n0 = blockIdx.x * 128;
    int tid = threadIdx.x;
    int lane = tid & 63, wave = tid >> 6;
    int wm = (wave >> 1) * 64, wn = (wave & 1) * 64;
    int l15 = lane & 15, quad = lane >> 4;
    f32x4 acc[4][4];
    #pragma unroll
    for (int i = 0; i < 4; i++)
        #pragma unroll
        for (int j = 0; j < 4; j++) acc[i][j] = (f32x4){0.f, 0.f, 0.f, 0.f};

    int srow = tid >> 2;
    int schunk = (tid & 3) * 8;

    for (int k0 = 0; k0 < K; k0 += 32) {
        #pragma unroll
        for (int ps = 0; ps < 2; ps++) {
            int r = srow + ps * 64;
            *(uint4*)&As[r][schunk] = *(const uint4*)&A[(size_t)(m0 + r) * K + k0 + schunk];
            *(uint4*)&Bs[r][schunk] = *(const uint4*)&Bt[(size_t)(n0 + r) * K + k0 + schunk];
        }
        __syncthreads();
        bf16x8 af[4], bfr[4];
        #pragma unroll
        for (int i = 0; i < 4; i++) af[i]  = *(const bf16x8*)&As[wm + i * 16 + l15][quad * 8];
        #pragma unroll
        for (int j = 0; j < 4; j++) bfr[j] = *(const bf16x8*)&Bs[wn + j * 16 + l15][quad * 8];
        #pragma unroll
        for (int i = 0; i < 4; i++)
            #pragma unroll
            for (int j = 0; j < 4; j++)
                acc[i][j] = __builtin_amdgcn_mfma_f32_16x16x32_bf16(af[i], bfr[j], acc[i][j], 0, 0, 0);
        __syncthreads();
    }
    #pragma unroll
    for (int i = 0; i < 4; i++) {
        #pragma unroll
        for (int j = 0; j < 4; j++) {
            int col = n0 + wn + j * 16 + l15;
            if (col < N) {
                #pragma unroll
                for (int r = 0; r < 4; r++) {
                    int row = m0 + wm + i * 16 + quad * 4 + r;
                    C[(size_t)row * N + col] = acc[i][j][r];
                }
            }
        }
    }
}

// batched K/V projection
__global__ __launch_bounds__(256)
void k_gemm_kv(const unsigned short* __restrict__ A, const unsigned short* __restrict__ Kwt,
               const unsigned short* __restrict__ Vwt, float* __restrict__ Kb,
               float* __restrict__ Vb) {
    int z = blockIdx.z; int layer = z >> 1; int which = z & 1;
    const unsigned short* Bt = (which ? Vwt : Kwt) + (size_t)layer * AINNER * D_MODEL;
    float* C = (which ? Vb : Kb) + (size_t)layer * (BSZ * LC) * AINNER;
    __shared__ unsigned short As[128][40];
    __shared__ unsigned short Bs[128][40];
    int n0 = blockIdx.x * 128;
    int tid = threadIdx.x;
    int lane = tid & 63, wave = tid >> 6;
    int wm = (wave >> 1) * 64, wn = (wave & 1) * 64;
    int l15 = lane & 15, quad = lane >> 4;
    f32x4 acc[4][4];
    #pragma unroll
    for (int i = 0; i < 4; i++)
        #pragma unroll
        for (int j = 0; j < 4; j++) acc[i][j] = (f32x4){0.f, 0.f, 0.f, 0.f};
    int srow = tid >> 2, schunk = (tid & 3) * 8;
    for (int k0 = 0; k0 < D_MODEL; k0 += 32) {
        #pragma unroll
        for (int ps = 0; ps < 2; ps++) {
            int r = srow + ps * 64;
            *(uint4*)&As[r][schunk] = *(const uint4*)&A[(size_t)r * D_MODEL + k0 + schunk];
            *(uint4*)&Bs[r][schunk] = *(const uint4*)&Bt[(size_t)(n0 + r) * D_MODEL + k0 + schunk];
        }
        __syncthreads();
        bf16x8 af[4], bfr[4];
        #pragma unroll
        for (int i = 0; i < 4; i++) af[i]  = *(const bf16x8*)&As[wm + i * 16 + l15][quad * 8];
        #pragma unroll
        for (int j = 0; j < 4; j++) bfr[j] = *(const bf16x8*)&Bs[wn + j * 16 + l15][quad * 8];
        #pragma unroll
        for (int i = 0; i < 4; i++)
            #pragma unroll
            for (int j = 0; j < 4; j++)
                acc[i][j] = __builtin_amdgcn_mfma_f32_16x16x32_bf16(af[i], bfr[j], acc[i][j], 0, 0, 0);
        __syncthreads();
    }
    #pragma unroll
    for (int i = 0; i < 4; i++) {
        #pragma unroll
        for (int j = 0; j < 4; j++) {
            int col = n0 + wn + j * 16 + l15;
            #pragma unroll
            for (int r = 0; r < 4; r++) {
                int row = wm + i * 16 + quad * 4 + r;
                C[(size_t)row * AINNER + col] = acc[i][j][r];
            }
        }
    }
}

// ---------------- silu(mean(cond, axis=1)) ----------------
__global__ void k_silumean(const float* __restrict__ cond, float* __restrict__ smc) {
    int i = blockIdx.x * 256 + threadIdx.x;
    if (i >= BSZ * D_MODEL) return;
    int b = i / D_MODEL, d = i % D_MODEL;
    const float* p = cond + (size_t)b * LC * D_MODEL + d;
    float s = 0.f;
    #pragma unroll 4
    for (int l = 0; l < LC; l++) s += p[l * D_MODEL];
    s *= (1.f / (float)LC);
    smc[i] = siluf(s);
}

// ---------------- aff_all init with bias ----------------
__global__ void k_ada_init(const float* __restrict__ adab, float* __restrict__ aff_all) {
    int i = blockIdx.x * 256 + threadIdx.x;
    if (i >= N_LAYER * BSZ * AFF) return;
    int j = i % AFF; int lb = i / AFF; int l = lb >> 1;
    aff_all[i] = adab[l * AFF + j];
}

// ---------------- split-K ada ----------------
__global__ void k_ada_split(const float* __restrict__ smc, const float* __restrict__ adaw,
                            float* __restrict__ aff_all) {
    int l = blockIdx.z;
    int kc = blockIdx.y;
    int j = blockIdx.x * 256 + threadIdx.x;
    const float* w = adaw + (size_t)l * D_MODEL * AFF + j;
    const float* x0 = smc;
    const float* x1 = smc + D_MODEL;
    float s0 = 0.f, s1 = 0.f;
    int d0 = kc * 96;
    #pragma unroll 8
    for (int d = d0; d < d0 + 96; d++) {
        float wv = w[(size_t)d * AFF];
        s0 += x0[d] * wv; s1 += x1[d] * wv;
    }
    atomicAdd(&aff_all[(size_t)l * BSZ * AFF + j], s0);
    atomicAdd(&aff_all[(size_t)l * BSZ * AFF + AFF + j], s1);
}

// ---------------- [fused prev-attn out] + residual update + rmsnorm + mod ----------------
__global__ void k_addrmsmod(const float* __restrict__ hin, const float* __restrict__ raw,
                            const float* __restrict__ bias, const float* __restrict__ affprev,
                            float* __restrict__ residual, const float* __restrict__ normw,
                            const float* __restrict__ affcur,
                            float* __restrict__ hidden_n, unsigned short* __restrict__ u,
                            int has_raw) {
    __shared__ float s4[4];
    int row = blockIdx.x;
    int b = row >> 9;
    const float* hp = hin + (size_t)row * D_MODEL;
    float* rp = residual + (size_t)row * D_MODEL;
    float v[3]; float ss = 0.f;
    #pragma unroll
    for (int j = 0; j < 3; j++) {
        int d = threadIdx.x + j * 256;
        float x = hp[d];
        if (has_raw) {
            float g = affprev[b * AFF + 3840 + d];
            x += g * (raw[(size_t)row * D_MODEL + d] + bias[d]);
        }
        x += rp[d];
        rp[d] = x; v[j] = x; ss += x * x;
    }
    ss = block_sum_256(ss, s4);
    float inv = rsqrtf(ss / (float)D_MODEL + 1e-5f);
    const float* sh = affcur + b * AFF;
    const float* sc = affcur + b * AFF + 768;
    #pragma unroll
    for (int j = 0; j < 3; j++) {
        int d = threadIdx.x + j * 256;
        float hn = v[j] * inv * normw[d];
        hidden_n[(size_t)row * D_MODEL + d] = hn;
        u[(size_t)row * D_MODEL + d] = f2b(hn * (1.f + sc[d]) + sh[d]);
    }
}

// ---------------- depthwise causal conv + silu, fused softplus(dt) ----------------
__global__ void k_convdt(const float* __restrict__ zx, const float* __restrict__ convw,
                         const float* __restrict__ convb, const float* __restrict__ dtbias,
                         float* __restrict__ xBC, float* __restrict__ dtb) {
    int i = blockIdx.x * 256 + threadIdx.x;
    if (i < ROWS * NHEADS) {
        int h = i % NHEADS; int row = i / NHEADS;
        float x = zx[(size_t)row * D_IN_PROJ + D_INNER + CONV_DIM + h] + dtbias[h];
        dtb[i] = (x > 20.f) ? x : log1pf(expf(x));
    }
    if (i >= ROWS * CONV_DIM) return;
    int c = i % CONV_DIM; int row = i / CONV_DIM;
    int l = row & 511; int b = row >> 9;
    float acc = convb[c];
    #pragma unroll
    for (int k = 0; k < 4; k++) {
        int t = l - 3 + k;
        if (t >= 0)
            acc += convw[c * 4 + k] * zx[(size_t)(b * SEQ + t) * D_IN_PROJ + D_INNER + c];
    }
    xBC[i] = siluf(acc);
}

// ---------------- S1: per-chunk end state via MFMA ----------------
// S[p][n] = sum_t (dt_t*exp(L_end-L_t)) * X[t][p] * B[t][n]
__global__ __launch_bounds__(256)
void k_ssm_state(const float* __restrict__ xBC, const float* __restrict__ dtb,
                 const float* __restrict__ Alog, float* __restrict__ Sbuf,
                 float* __restrict__ Pbuf) {
    int blk = blockIdx.x;
    int c = blk & (NCHUNK - 1); int bh = blk >> 3;
    int h = bh % NHEADS; int b = bh / NHEADS;
    int tid = threadIdx.x;
    __shared__ unsigned short sXwT[64][72];   // [p][t], scaled by w_t
    __shared__ unsigned short sBT[128][72];   // [n][t]
    __shared__ float sL[64], sDt[64];
    int base = b * SEQ + c * CT;
    int r = tid >> 2, q4 = tid & 3;
    if (tid < 64) {
        float dt = dtb[(base + tid) * NHEADS + h];
        float a = expf(Alog[h]);
        float v = -a * dt;
        #pragma unroll
        for (int off = 1; off < 64; off <<= 1) {
            float u2 = __shfl_up(v, off, 64);
            if (tid >= off) v += u2;
        }
        sL[tid] = v; sDt[tid] = dt;
    }
    __syncthreads();
    float Lend = sL[63];
    if (tid == 0) Pbuf[blk] = expf(Lend);
    float wr = expf(Lend - sL[r]) * sDt[r];
    const float* xrow = xBC + (size_t)(base + r) * CONV_DIM;
    #pragma unroll
    for (int j = 0; j < 4; j++) {
        float4 v = *(const float4*)&xrow[h * HEADDIM + q4 * 16 + j * 4];
        int p0 = q4 * 16 + j * 4;
        sXwT[p0 + 0][r] = f2b(v.x * wr); sXwT[p0 + 1][r] = f2b(v.y * wr);
        sXwT[p0 + 2][r] = f2b(v.z * wr); sXwT[p0 + 3][r] = f2b(v.w * wr);
    }
    #pragma unroll
    for (int j = 0; j < 8; j++) {
        float4 v = *(const float4*)&xrow[D_INNER + q4 * 32 + j * 4];
        int n0 = q4 * 32 + j * 4;
        sBT[n0 + 0][r] = f2b(v.x); sBT[n0 + 1][r] = f2b(v.y);
        sBT[n0 + 2][r] = f2b(v.z); sBT[n0 + 3][r] = f2b(v.w);
    }
    __syncthreads();
    int lane = tid & 63, wave = tid >> 6;
    int l15 = lane & 15, quad = lane >> 4;
    f32x4 acc[8];
    #pragma unroll
    for (int j = 0; j < 8; j++) acc[j] = (f32x4){0.f, 0.f, 0.f, 0.f};
    #pragma unroll
    for (int k0 = 0; k0 < 2; k0++) {
        bf16x8 a = *(const bf16x8*)&sXwT[wave * 16 + l15][k0 * 32 + quad * 8];
        #pragma unroll
        for (int nt = 0; nt < 8; nt++) {
            bf16x8 bv = *(const bf16x8*)&sBT[nt * 16 + l15][k0 * 32 + quad * 8];
            acc[nt] = __builtin_amdgcn_mfma_f32_16x16x32_bf16(a, bv, acc[nt], 0, 0, 0);
        }
    }
    float* sout = Sbuf + (size_t)blk * 8192;
    #pragma unroll
    for (int nt = 0; nt < 8; nt++) {
        int n = nt * 16 + l15;
        #pragma unroll
        for (int rr = 0; rr < 4; rr++) {
            int p = wave * 16 + quad * 4 + rr;
            sout[p * 128 + n] = acc[nt][rr];
        }
    }
}

// ---------------- S2: sequential chunk recurrence ----------------
__global__ void k_ssm_seq(const float* __restrict__ Sbuf, const float* __restrict__ Pbuf,
                          unsigned short* __restrict__ hstart) {
    int bh = blockIdx.x >> 5; int part = blockIdx.x & 31;
    int idx = part * 256 + threadIdx.x;
    float h = 0.f;
    #pragma unroll
    for (int c = 0; c < NCHUNK; c++) {
        size_t o = ((size_t)bh * NCHUNK + c) * 8192 + idx;
        hstart[o] = f2b(h);
        h = h * Pbuf[bh * NCHUNK + c] + Sbuf[o];
    }
}

// ---------------- S3: chunk outputs via MFMA ----------------
__global__ __launch_bounds__(256)
void k_ssm_out(const float* __restrict__ xBC, const float* __restrict__ dtb,
               const float* __restrict__ Alog, const float* __restrict__ Dssm,
               const unsigned short* __restrict__ hstart, float* __restrict__ y) {
    int blk = blockIdx.x;
    int c = blk & (NCHUNK - 1); int bh = blk >> 3;
    int h = bh % NHEADS; int b = bh / NHEADS;
    int tid = threadIdx.x;
    __shared__ unsigned short sB[64][136];    // [t][n]; reused for hstart [p][n]
    __shared__ unsigned short sC[64][136];    // [t][n]; scaled by exp(L_t) after pass 1
    __shared__ unsigned short sXT[64][72];    // [p][t]
    __shared__ unsigned short sG[64][72];     // [i][s] masked decay-scaled
    __shared__ float sL[64], sDt[64];
    int base = b * SEQ + c * CT;
    int r = tid >> 2, q4 = tid & 3;
    if (tid < 64) {
        float dt = dtb[(base + tid) * NHEADS + h];
        float a = expf(Alog[h]);
        float v = -a * dt;
        #pragma unroll
        for (int off = 1; off < 64; off <<= 1) {
            float u2 = __shfl_up(v, off, 64);
            if (tid >= off) v += u2;
        }
        sL[tid] = v; sDt[tid] = dt;
    }
    const float* xrow = xBC + (size_t)(base + r) * CONV_DIM;
    // stage B, C as [t][n]
    #pragma unroll
    for (int j = 0; j < 8; j++) {
        float4 v = *(const float4*)&xrow[D_INNER + q4 * 32 + j * 4];
        int n0 = q4 * 32 + j * 4;
        ushort4 pk; pk.x = f2b(v.x); pk.y = f2b(v.y); pk.z = f2b(v.z); pk.w = f2b(v.w);
        *(ushort4*)&sB[r][n0] = pk;
        float4 w = *(const float4*)&xrow[D_INNER + D_STATE + q4 * 32 + j * 4];
        ushort4 pk2; pk2.x = f2b(w.x); pk2.y = f2b(w.y); pk2.z = f2b(w.z); pk2.w = f2b(w.w);
        *(ushort4*)&sC[r][n0] = pk2;
    }
    // stage X transposed [p][t]
    #pragma unroll
    for (int j = 0; j < 4; j++) {
        float4 v = *(const float4*)&xrow[h * HEADDIM + q4 * 16 + j * 4];
        int p0 = q4 * 16 + j * 4;
        sXT[p0 + 0][r] = f2b(v.x); sXT[p0 + 1][r] = f2b(v.y);
        sXT[p0 + 2][r] = f2b(v.z); sXT[p0 + 3][r] = f2b(v.w);
    }
    // hstart -> registers (written into sB after pass 1)
    const unsigned short* hsrc = hstart + ((size_t)bh * NCHUNK + c) * 8192;
    uint4 hreg[4];
    #pragma unroll
    for (int j = 0; j < 4; j++)
        hreg[j] = *(const uint4*)&hsrc[r * 128 + q4 * 32 + j * 8];
    __syncthreads();

    int lane = tid & 63, wave = tid >> 6;
    int l15 = lane & 15, quad = lane >> 4;
    // ---- pass 1: G_raw = C . B^T  (M=64 i, N=64 s, K=128 n) ----
    f32x4 acc1[4];
    #pragma unroll
    for (int j = 0; j < 4; j++) acc1[j] = (f32x4){0.f, 0.f, 0.f, 0.f};
    #pragma unroll
    for (int k0 = 0; k0 < 4; k0++) {
        bf16x8 a = *(const bf16x8*)&sC[wave * 16 + l15][k0 * 32 + quad * 8];
        #pragma unroll
        for (int nt = 0; nt < 4; nt++) {
            bf16x8 bv = *(const bf16x8*)&sB[nt * 16 + l15][k0 * 32 + quad * 8];
            acc1[nt] = __builtin_amdgcn_mfma_f32_16x16x32_bf16(a, bv, acc1[nt], 0, 0, 0);
        }
    }
    // mask + decay -> sG (bf16); rows wave*16..+15 are wave-exclusive
    #pragma unroll
    for (int nt = 0; nt < 4; nt++) {
        int s = nt * 16 + l15;
        float Ls = sL[s], dts = sDt[s];
        #pragma unroll
        for (int rr = 0; rr < 4; rr++) {
            int i = wave * 16 + quad * 4 + rr;
            float g = (s <= i) ? acc1[nt][rr] * expf(sL[i] - Ls) * dts : 0.f;
            sG[i][s] = f2b(g);
        }
    }
    // scale own sC rows by exp(L_i) for pass 3 (wave-exclusive rows)
    {
        int row = wave * 16 + l15;
        float el = expf(sL[row]);
        #pragma unroll
        for (int j = 0; j < 32; j++) {
            int n = quad * 32 + j;
            sC[row][n] = f2b(b2f(sC[row][n]) * el);
        }
    }
    __syncthreads();   // all pass-1 reads of sB done
    #pragma unroll
    for (int j = 0; j < 4; j++)
        *(uint4*)&sB[r][q4 * 32 + j * 8] = hreg[j];     // sB now holds hstart [p][n]
    __syncthreads();

    // ---- pass 2: Y = G . X  (K=64 s) ;  pass 3: Y += Ce . hstart^T (K=128 n) ----
    f32x4 acc2[4];
    #pragma unroll
    for (int j = 0; j < 4; j++) acc2[j] = (f32x4){0.f, 0.f, 0.f, 0.f};
    #pragma unroll
    for (int k0 = 0; k0 < 2; k0++) {
        bf16x8 a = *(const bf16x8*)&sG[wave * 16 + l15][k0 * 32 + quad * 8];
        #pragma unroll
        for (int nt = 0; nt < 4; nt++) {
            bf16x8 bv = *(const bf16x8*)&sXT[nt * 16 + l15][k0 * 32 + quad * 8];
            acc2[nt] = __builtin_amdgcn_mfma_f32_16x16x32_bf16(a, bv, acc2[nt], 0, 0, 0);
        }
    }
    #pragma unroll
    for (int k0 = 0; k0 < 4; k0++) {
        bf16x8 a = *(const bf16x8*)&sC[wave * 16 + l15][k0 * 32 + quad * 8];
        #pragma unroll
        for (int nt = 0; nt < 4; nt++) {
            bf16x8 bv = *(const bf16x8*)&sB[nt * 16 + l15][k0 * 32 + quad * 8];
            acc2[nt] = __builtin_amdgcn_mfma_f32_16x16x32_bf16(a, bv, acc2[nt], 0, 0, 0);
        }
    }
    // epilogue: + D*x, store
    float Dh = Dssm[h];
    #pragma unroll
    for (int nt = 0; nt < 4; nt++) {
        int p = nt * 16 + l15;
        #pragma unroll
        for (int rr = 0; rr < 4; rr++) {
            int i = wave * 16 + quad * 4 + rr;
            float xv = b2f(sXT[p][i]);
            y[(size_t)(base + i) * D_INNER + h * HEADDIM + p] = acc2[nt][rr] + Dh * xv;
        }
    }
}

// ---------------- gated rmsnorm -> bf16 ----------------
__global__ void k_gatednorm(const float* __restrict__ yscan, const float* __restrict__ zx,
                            const float* __restrict__ nw, unsigned short* __restrict__ out) {
    __shared__ float s4[4];
    int row = blockIdx.x;
    const float* yp = yscan + (size_t)row * D_INNER;
    const float* zp = zx + (size_t)row * D_IN_PROJ;
    float v[6]; float ss = 0.f;
    #pragma unroll
    for (int j = 0; j < 6; j++) {
        int d = threadIdx.x + j * 256;
        float val = yp[d] * siluf(zp[d]);
        v[j] = val; ss += val * val;
    }
    ss = block_sum_256(ss, s4);
    float inv = rsqrtf(ss / (float)D_INNER + 1e-5f);
    #pragma unroll
    for (int j = 0; j < 6; j++) {
        int d = threadIdx.x + j * 256;
        out[(size_t)row * D_INNER + d] = f2b(v[j] * inv * nw[d]);
    }
}

// ---------------- hidden2 = hidden_n + g_mba*(tmp+out_b); ln_noaffine + msa mod -> bf16 ----
__global__ void k_fuse_ln(const float* __restrict__ hidden_n, const float* __restrict__ tmp,
                          const float* __restrict__ outb, const float* __restrict__ aff,
                          float* __restrict__ hidden2, unsigned short* __restrict__ attnx) {
    __shared__ float s4[4];
    int row = blockIdx.x;
    int b = row >> 9;
    const float* gm = aff + b * AFF + 1536;
    float v[3]; float s = 0.f;
    #pragma unroll
    for (int j = 0; j < 3; j++) {
        int d = threadIdx.x + j * 256;
        float x = hidden_n[(size_t)row * D_MODEL + d]
                + gm[d] * (tmp[(size_t)row * D_MODEL + d] + outb[d]);
        hidden2[(size_t)row * D_MODEL + d] = x;
        v[j] = x; s += x;
    }
    float mean = block_sum_256(s, s4) / (float)D_MODEL;
    float ss = 0.f;
    #pragma unroll
    for (int j = 0; j < 3; j++) { float c = v[j] - mean; ss += c * c; }
    float var = block_sum_256(ss, s4) / (float)D_MODEL;
    float inv = rsqrtf(var + 1e-6f);
    const float* sh = aff + b * AFF + 2304;
    const float* sc = aff + b * AFF + 3072;
    #pragma unroll
    for (int j = 0; j < 3; j++) {
        int d = threadIdx.x + j * 256;
        float xh = (v[j] - mean) * inv;
        attnx[(size_t)row * D_MODEL + d] = f2b(xh * (1.f + sc[d]) + sh[d]);
    }
}

// ---------------- cross-attention core -> ob bf16 ----------------
__global__ __launch_bounds__(64)
void k_attn(const float* __restrict__ q, const float* __restrict__ k,
            const float* __restrict__ v, unsigned short* __restrict__ o) {
    int blk = blockIdx.x;
    int l = blk & 511; int h = (blk >> 9) & 7; int b = blk >> 12;
    int m = threadIdx.x;
    const float* qp = q + ((size_t)(b * SEQ + l) * AH + h) * AD;
    const float* kp = k + ((size_t)(b * LC + m) * AH + h) * AD;
    float s = 0.f;
    #pragma unroll 8
    for (int d = 0; d < AD; d++) s += qp[d] * kp[d];
    s *= 0.125f;
    float mx = s;
    #pragma unroll
    for (int off = 32; off > 0; off >>= 1) mx = fmaxf(mx, __shfl_xor(mx, off, 64));
    float e = expf(s - mx);
    float sum = e;
    #pragma unroll
    for (int off = 32; off > 0; off >>= 1) sum += __shfl_xor(sum, off, 64);
    float a = e / sum;
    __shared__ float sa[64];
    sa[m] = a;
    __syncthreads();
    int d = threadIdx.x;
    float acc = 0.f;
    #pragma unroll 8
    for (int mm = 0; mm < LC; mm++)
        acc += sa[mm] * v[((size_t)(b * LC + mm) * AH + h) * AD + d];
    o[((size_t)(b * SEQ + l) * AH + h) * AD + d] = f2b(acc);
}

// ---------------- final: h = hidden2 + g*(raw+bias); rmsnorm(h + r) ----------------
__global__ void k_final(const float* __restrict__ hidden2, const float* __restrict__ raw,
                        const float* __restrict__ bias, const float* __restrict__ aff,
                        const float* __restrict__ residual, const float* __restrict__ w,
                        float* __restrict__ out) {
    __shared__ float s4[4];
    int row = blockIdx.x;
    int b = row >> 9;
    const float* gm = aff + b * AFF + 3840;
    float v[3]; float ss = 0.f;
    #pragma unroll
    for (int j = 0; j < 3; j++) {
        int d = threadIdx.x + j * 256;
        float x = hidden2[(size_t)row * D_MODEL + d]
                + gm[d] * (raw[(size_t)row * D_MODEL + d] + bias[d])
                + residual[(size_t)row * D_MODEL + d];
        v[j] = x; ss += x * x;
    }
    ss = block_sum_256(ss, s4);
    float inv = rsqrtf(ss / (float)D_MODEL + 1e-5f);
    #pragma unroll
    for (int j = 0; j < 3; j++) {
        int d = threadIdx.x + j * 256;
        out[(size_t)row * D_MODEL + d] = v[j] * inv * w[d];
    }
}

// ---------------- host launch ----------------
extern "C" void kernel_launch(void* const* d_in, const int* in_sizes, int n_in,
                              void* d_out, int out_size, void* d_ws, size_t ws_size,
                              hipStream_t stream) {
    const float* hidden_states = (const float*)d_in[0];
    const float* ref_emb  = (const float*)d_in[1];
    const float* norm_w   = (const float*)d_in[2];
    const float* ada_w    = (const float*)d_in[3];
    const float* ada_b    = (const float*)d_in[4];
    const float* in_w     = (const float*)d_in[5];
    const float* conv_w   = (const float*)d_in[6];
    const float* conv_b   = (const float*)d_in[7];
    const float* dt_bias  = (const float*)d_in[8];
    const float* A_log    = (const float*)d_in[9];
    const float* D_ssm    = (const float*)d_in[10];
    const float* ssm_nw   = (const float*)d_in[11];
    const float* out_w    = (const float*)d_in[12];
    const float* out_b    = (const float*)d_in[13];
    const float* q_w      = (const float*)d_in[14];
    const float* k_w      = (const float*)d_in[15];
    const float* v_w      = (const float*)d_in[16];
    const float* o_w      = (const float*)d_in[17];
    const float* o_b      = (const float*)d_in[18];
    const float* norm_f_w = (const float*)d_in[19];
    float* out = (float*)d_out;

    char* p = (char*)d_ws;
    auto alloc = [&](size_t bytes) -> char* {
        char* r = p; p += (bytes + 255) & ~(size_t)255; return r;
    };
    float* residual = (float*)alloc((size_t)ROWS * D_MODEL * 4);
    float* hidden2  = (float*)alloc((size_t)ROWS * D_MODEL * 4);
    float* hidden_n = (float*)alloc((size_t)ROWS * D_MODEL * 4);
    float* tmp      = (float*)alloc((size_t)ROWS * D_MODEL * 4);
    float* zx       = (float*)alloc((size_t)ROWS * D_IN_PROJ * 4);
    float* xBC      = (float*)alloc((size_t)ROWS * CONV_DIM * 4);
    float* dtb      = (float*)alloc((size_t)ROWS * NHEADS * 4);
    float* yscan    = (float*)alloc((size_t)ROWS * D_INNER * 4);
    float* qb       = (float*)alloc((size_t)ROWS * AINNER * 4);
    float* kb_all   = (float*)alloc((size_t)N_LAYER * BSZ * LC * AINNER * 4);
    float* vb_all   = (float*)alloc((size_t)N_LAYER * BSZ * LC * AINNER * 4);
    float* aff_all  = (float*)alloc((size_t)N_LAYER * BSZ * AFF * 4);
    float* smc      = (float*)alloc((size_t)BSZ * D_MODEL * 4);
    float* Sbuf     = (float*)alloc((size_t)BSZ * NHEADS * NCHUNK * 8192 * 4);
    float* Pbuf     = (float*)alloc((size_t)BSZ * NHEADS * NCHUNK * 4);
    unsigned short* hstart = (unsigned short*)alloc((size_t)BSZ * NHEADS * NCHUNK * 8192 * 2);
    unsigned short* u_bf   = (unsigned short*)alloc((size_t)ROWS * D_MODEL * 2);
    unsigned short* ynorm  = (unsigned short*)alloc((size_t)ROWS * D_INNER * 2);
    unsigned short* attnx  = (unsigned short*)alloc((size_t)ROWS * D_MODEL * 2);
    unsigned short* ob     = (unsigned short*)alloc((size_t)ROWS * AINNER * 2);
    unsigned short* ref_bf = (unsigned short*)alloc((size_t)BSZ * LC * D_MODEL * 2);
    unsigned short* in_wt  = (unsigned short*)alloc((size_t)NP1 * D_MODEL * 2);
    unsigned short* out_wt = (unsigned short*)alloc((size_t)D_MODEL * D_INNER * 2);
    unsigned short* q_wt   = (unsigned short*)alloc((size_t)AINNER * D_MODEL * 2);
    unsigned short* o_wt   = (unsigned short*)alloc((size_t)D_MODEL * AINNER * 2);
    unsigned short* kwt_all = (unsigned short*)alloc((size_t)N_LAYER * AINNER * D_MODEL * 2);
    unsigned short* vwt_all = (unsigned short*)alloc((size_t)N_LAYER * AINNER * D_MODEL * 2);

    hipMemsetAsync(residual, 0, (size_t)ROWS * D_MODEL * sizeof(float), stream);
    k_silumean<<<(BSZ * D_MODEL + 255) / 256, 256, 0, stream>>>(ref_emb, smc);
    k_f2b<<<(BSZ * LC * D_MODEL + 255) / 256, 256, 0, stream>>>(ref_emb, ref_bf, BSZ * LC * D_MODEL);
    k_ada_init<<<(N_LAYER * BSZ * AFF + 255) / 256, 256, 0, stream>>>(ada_b, aff_all);
    k_ada_split<<<dim3(AFF / 256, 8, N_LAYER), 256, 0, stream>>>(smc, ada_w, aff_all);
    k_transpose_b<<<dim3(AINNER / 32, D_MODEL / 32, N_LAYER), 256, 0, stream>>>(k_w, kwt_all, D_MODEL, AINNER);
    k_transpose_b<<<dim3(AINNER / 32, D_MODEL / 32, N_LAYER), 256, 0, stream>>>(v_w, vwt_all, D_MODEL, AINNER);
    k_gemm_kv<<<dim3(AINNER / 128, 1, N_LAYER * 2), 256, 0, stream>>>(ref_bf, kwt_all, vwt_all, kb_all, vb_all);

    for (int layer = 0; layer < N_LAYER; layer++) {
        const float* L_norm_w  = norm_w  + layer * D_MODEL;
        const float* L_in_w    = in_w    + (size_t)layer * D_MODEL * D_IN_PROJ;
        const float* L_conv_w  = conv_w  + layer * CONV_DIM * 4;
        const float* L_conv_b  = conv_b  + layer * CONV_DIM;
        const float* L_dt_bias = dt_bias + layer * NHEADS;
        const float* L_A_log   = A_log   + layer * NHEADS;
        const float* L_D_ssm   = D_ssm   + layer * NHEADS;
        const float* L_ssm_nw  = ssm_nw  + layer * D_INNER;
        const float* L_out_w   = out_w   + (size_t)layer * D_INNER * D_MODEL;
        const float* L_out_b   = out_b   + layer * D_MODEL;
        const float* L_q_w     = q_w     + (size_t)layer * D_MODEL * AINNER;
        const float* L_o_w     = o_w     + (size_t)layer * AINNER * D_MODEL;
        const float* L_o_b_prev= o_b     + (layer - 1) * D_MODEL;
        const float* L_aff     = aff_all + (size_t)layer * BSZ * AFF;
        const float* L_aff_prev= aff_all + (size_t)(layer - 1) * BSZ * AFF;

        k_transpose<<<dim3(NP1 / 32, D_MODEL / 32), 256, 0, stream>>>(L_in_w, in_wt, D_MODEL, D_IN_PROJ);
        k_transpose<<<dim3(D_MODEL / 32, D_INNER / 32), 256, 0, stream>>>(L_out_w, out_wt, D_INNER, D_MODEL);
        k_transpose<<<dim3(AINNER / 32, D_MODEL / 32), 256, 0, stream>>>(L_q_w, q_wt, D_MODEL, AINNER);
        k_transpose<<<dim3(D_MODEL / 32, AINNER / 32), 256, 0, stream>>>(L_o_w, o_wt, AINNER, D_MODEL);

        k_addrmsmod<<<ROWS, 256, 0, stream>>>(
            layer == 0 ? hidden_states : hidden2, tmp,
            layer == 0 ? o_b : L_o_b_prev,
            layer == 0 ? aff_all : L_aff_prev,
            residual, L_norm_w, L_aff, hidden_n, u_bf, layer == 0 ? 0 : 1);
        k_gemm<<<dim3(NP1 / 128, ROWS / 128), 256, 0, stream>>>(u_bf, in_wt, zx, ROWS, D_IN_PROJ, D_MODEL);
        k_convdt<<<(ROWS * CONV_DIM + 255) / 256, 256, 0, stream>>>(zx, L_conv_w, L_conv_b, L_dt_bias, xBC, dtb);
        k_ssm_state<<<BSZ * NHEADS * NCHUNK, 256, 0, stream>>>(xBC, dtb, L_A_log, Sbuf, Pbuf);
        k_ssm_seq<<<BSZ * NHEADS * 32, 256, 0, stream>>>(Sbuf, Pbuf, hstart);
        k_ssm_out<<<BSZ * NHEADS * NCHUNK, 256, 0, stream>>>(xBC, dtb, L_A_log, L_D_ssm, hstart, yscan);
        k_gatednorm<<<ROWS, 256, 0, stream>>>(yscan, zx, L_ssm_nw, ynorm);
        k_gemm<<<dim3(D_MODEL / 128, ROWS / 128), 256, 0, stream>>>(ynorm, out_wt, tmp, ROWS, D_MODEL, D_INNER);
        k_fuse_ln<<<ROWS, 256, 0, stream>>>(hidden_n, tmp, L_out_b, L_aff, hidden2, attnx);
        k_gemm<<<dim3(AINNER / 128, ROWS / 128), 256, 0, stream>>>(attnx, q_wt, qb, ROWS, AINNER, D_MODEL);
        k_attn<<<BSZ * AH * SEQ, 64, 0, stream>>>(
            qb, kb_all + (size_t)layer * BSZ * LC * AINNER,
            vb_all + (size_t)layer * BSZ * LC * AINNER, ob);
        k_gemm<<<dim3(D_MODEL / 128, ROWS / 128), 256, 0, stream>>>(ob, o_wt, tmp, ROWS, D_MODEL, AINNER);
    }
    k_final<<<ROWS, 256, 0, stream>>>(hidden2, tmp, o_b + (N_LAYER - 1) * D_MODEL,
                                      aff_all + (size_t)(N_LAYER - 1) * BSZ * AFF,
                                      residual, norm_f_w, out);
}

// Round 5
// 1772.168 us; speedup vs baseline: 8.0678x; 1.0528x over previous
//
#include <hip/hip_runtime.h>
#include <hip/hip_bf16.h>
#include <math.h>

// ---------------- constants ----------------
#define D_MODEL   768
#define N_LAYER   8
#define D_INNER   1536
#define D_STATE   128
#define HEADDIM   64
#define NHEADS    24
#define CONV_DIM  1792
#define D_IN_PROJ 3352
#define AH        8
#define AD        64
#define AINNER    512
#define BSZ       2
#define SEQ       512
#define LC        64
#define ROWS      (BSZ*SEQ)          // 1024
#define NCHUNK    8
#define CT        64                 // chunk length
#define NP1       3456               // 3352 padded to 27*128
#define AFF       4608

typedef __attribute__((ext_vector_type(8))) short bf16x8;
typedef __attribute__((ext_vector_type(4))) float f32x4;

__device__ __forceinline__ float siluf(float x) { return x / (1.f + expf(-x)); }

__device__ __forceinline__ unsigned short f2b(float x) {
    __hip_bfloat16 h = __float2bfloat16(x);
    return __builtin_bit_cast(unsigned short, h);
}
__device__ __forceinline__ float b2f(unsigned short u) {
    unsigned v = ((unsigned)u) << 16;
    return __builtin_bit_cast(float, v);
}

// async global->LDS 16B copy (wave-uniform base + lane*16 contiguity honored by callers)
__device__ __forceinline__ void gload16(const void* g, void* l) {
    __builtin_amdgcn_global_load_lds(
        (const __attribute__((address_space(1))) unsigned int*)g,
        (__attribute__((address_space(3))) unsigned int*)l,
        16, 0, 0);
}

// block-wide sum, 256 threads (4 waves)
__device__ __forceinline__ float block_sum_256(float v, float* s4) {
    #pragma unroll
    for (int o = 32; o > 0; o >>= 1) v += __shfl_down(v, o, 64);
    __syncthreads();
    if ((threadIdx.x & 63) == 0) s4[threadIdx.x >> 6] = v;
    __syncthreads();
    return s4[0] + s4[1] + s4[2] + s4[3];
}

// ---------------- fp32 -> bf16 elementwise ----------------
__global__ void k_f2b(const float* __restrict__ src, unsigned short* __restrict__ dst, int n) {
    int i = blockIdx.x * 256 + threadIdx.x;
    if (i < n) dst[i] = f2b(src[i]);
}

// ---------------- batched padded transpose: src fp32 [L][K][N] -> dst bf16 [L][Npad][K] ----
__global__ void k_transpose_pb(const float* __restrict__ src, unsigned short* __restrict__ dst,
                               int K, int N, int Npad) {
    int z = blockIdx.z;
    src += (size_t)z * K * N;
    dst += (size_t)z * Npad * K;
    __shared__ float tile[32][33];
    int n0 = blockIdx.x * 32, k0 = blockIdx.y * 32;
    int t = threadIdx.x;
    int nl = t & 31, kl = t >> 5;
    #pragma unroll
    for (int p = 0; p < 4; p++) {
        int k = kl + p * 8;
        int n = n0 + nl;
        tile[k][nl] = (n < N) ? src[(size_t)(k0 + k) * N + n] : 0.f;
    }
    __syncthreads();
    int kl2 = t & 31, nl2 = t >> 5;
    #pragma unroll
    for (int p = 0; p < 4; p++) {
        int n = nl2 + p * 8;
        dst[(size_t)(n0 + n) * K + k0 + kl2] = f2b(tile[kl2][n]);
    }
}

// ---------------- bf16 MFMA GEMM with async LDS staging ----------------
// C[M,N] = A[M,K] @ Bt[N,K]^T ; A,Bt bf16 row-major; C fp32
__global__ __launch_bounds__(256)
void k_gemm(const unsigned short* __restrict__ A, const unsigned short* __restrict__ Bt,
            float* __restrict__ C, int M, int N, int K) {
    __shared__ __align__(16) unsigned short As[128][32];
    __shared__ __align__(16) unsigned short Bs[128][32];
    int m0 = blockIdx.y * 128, n0 = blockIdx.x * 128;
    int tid = threadIdx.x;
    int lane = tid & 63, wave = tid >> 6;
    int wm = (wave >> 1) * 64, wn = (wave & 1) * 64;
    int l15 = lane & 15, quad = lane >> 4;
    f32x4 acc[4][4];
    #pragma unroll
    for (int i = 0; i < 4; i++)
        #pragma unroll
        for (int j = 0; j < 4; j++) acc[i][j] = (f32x4){0.f, 0.f, 0.f, 0.f};

    int srow = tid >> 2;            // 0..63
    int schunk = (tid & 3) * 8;     // 0,8,16,24 (halfs)

    for (int k0 = 0; k0 < K; k0 += 32) {
        #pragma unroll
        for (int ps = 0; ps < 2; ps++) {
            int r = srow + ps * 64;
            gload16(&A[(size_t)(m0 + r) * K + k0 + schunk], &As[r][schunk]);
            gload16(&Bt[(size_t)(n0 + r) * K + k0 + schunk], &Bs[r][schunk]);
        }
        __syncthreads();
        bf16x8 af[4], bfr[4];
        #pragma unroll
        for (int i = 0; i < 4; i++) af[i]  = *(const bf16x8*)&As[wm + i * 16 + l15][quad * 8];
        #pragma unroll
        for (int j = 0; j < 4; j++) bfr[j] = *(const bf16x8*)&Bs[wn + j * 16 + l15][quad * 8];
        #pragma unroll
        for (int i = 0; i < 4; i++)
            #pragma unroll
            for (int j = 0; j < 4; j++)
                acc[i][j] = __builtin_amdgcn_mfma_f32_16x16x32_bf16(af[i], bfr[j], acc[i][j], 0, 0, 0);
        __syncthreads();
    }
    #pragma unroll
    for (int i = 0; i < 4; i++) {
        #pragma unroll
        for (int j = 0; j < 4; j++) {
            int col = n0 + wn + j * 16 + l15;
            if (col < N) {
                #pragma unroll
                for (int r = 0; r < 4; r++) {
                    int row = m0 + wm + i * 16 + quad * 4 + r;
                    C[(size_t)row * N + col] = acc[i][j][r];
                }
            }
        }
    }
}

// batched K/V projection -> bf16 out
__global__ __launch_bounds__(256)
void k_gemm_kv(const unsigned short* __restrict__ A, const unsigned short* __restrict__ Kwt,
               const unsigned short* __restrict__ Vwt, unsigned short* __restrict__ Kb,
               unsigned short* __restrict__ Vb) {
    int z = blockIdx.z; int layer = z >> 1; int which = z & 1;
    const unsigned short* Bt = (which ? Vwt : Kwt) + (size_t)layer * AINNER * D_MODEL;
    unsigned short* C = (which ? Vb : Kb) + (size_t)layer * (BSZ * LC) * AINNER;
    __shared__ __align__(16) unsigned short As[128][32];
    __shared__ __align__(16) unsigned short Bs[128][32];
    int n0 = blockIdx.x * 128;
    int tid = threadIdx.x;
    int lane = tid & 63, wave = tid >> 6;
    int wm = (wave >> 1) * 64, wn = (wave & 1) * 64;
    int l15 = lane & 15, quad = lane >> 4;
    f32x4 acc[4][4];
    #pragma unroll
    for (int i = 0; i < 4; i++)
        #pragma unroll
        for (int j = 0; j < 4; j++) acc[i][j] = (f32x4){0.f, 0.f, 0.f, 0.f};
    int srow = tid >> 2, schunk = (tid & 3) * 8;
    for (int k0 = 0; k0 < D_MODEL; k0 += 32) {
        #pragma unroll
        for (int ps = 0; ps < 2; ps++) {
            int r = srow + ps * 64;
            gload16(&A[(size_t)r * D_MODEL + k0 + schunk], &As[r][schunk]);
            gload16(&Bt[(size_t)(n0 + r) * D_MODEL + k0 + schunk], &Bs[r][schunk]);
        }
        __syncthreads();
        bf16x8 af[4], bfr[4];
        #pragma unroll
        for (int i = 0; i < 4; i++) af[i]  = *(const bf16x8*)&As[wm + i * 16 + l15][quad * 8];
        #pragma unroll
        for (int j = 0; j < 4; j++) bfr[j] = *(const bf16x8*)&Bs[wn + j * 16 + l15][quad * 8];
        #pragma unroll
        for (int i = 0; i < 4; i++)
            #pragma unroll
            for (int j = 0; j < 4; j++)
                acc[i][j] = __builtin_amdgcn_mfma_f32_16x16x32_bf16(af[i], bfr[j], acc[i][j], 0, 0, 0);
        __syncthreads();
    }
    #pragma unroll
    for (int i = 0; i < 4; i++) {
        #pragma unroll
        for (int j = 0; j < 4; j++) {
            int col = n0 + wn + j * 16 + l15;
            #pragma unroll
            for (int r = 0; r < 4; r++) {
                int row = wm + i * 16 + quad * 4 + r;
                C[(size_t)row * AINNER + col] = f2b(acc[i][j][r]);
            }
        }
    }
}

// ---------------- silu(mean(cond, axis=1)) ----------------
__global__ void k_silumean(const float* __restrict__ cond, float* __restrict__ smc) {
    int i = blockIdx.x * 256 + threadIdx.x;
    if (i >= BSZ * D_MODEL) return;
    int b = i / D_MODEL, d = i % D_MODEL;
    const float* p = cond + (size_t)b * LC * D_MODEL + d;
    float s = 0.f;
    #pragma unroll 4
    for (int l = 0; l < LC; l++) s += p[l * D_MODEL];
    s *= (1.f / (float)LC);
    smc[i] = siluf(s);
}

// ---------------- aff_all init with bias ----------------
__global__ void k_ada_init(const float* __restrict__ adab, float* __restrict__ aff_all) {
    int i = blockIdx.x * 256 + threadIdx.x;
    if (i >= N_LAYER * BSZ * AFF) return;
    int j = i % AFF; int lb = i / AFF; int l = lb >> 1;
    aff_all[i] = adab[l * AFF + j];
}

// ---------------- split-K ada ----------------
__global__ void k_ada_split(const float* __restrict__ smc, const float* __restrict__ adaw,
                            float* __restrict__ aff_all) {
    int l = blockIdx.z;
    int kc = blockIdx.y;
    int j = blockIdx.x * 256 + threadIdx.x;
    const float* w = adaw + (size_t)l * D_MODEL * AFF + j;
    const float* x0 = smc;
    const float* x1 = smc + D_MODEL;
    float s0 = 0.f, s1 = 0.f;
    int d0 = kc * 96;
    #pragma unroll 8
    for (int d = d0; d < d0 + 96; d++) {
        float wv = w[(size_t)d * AFF];
        s0 += x0[d] * wv; s1 += x1[d] * wv;
    }
    atomicAdd(&aff_all[(size_t)l * BSZ * AFF + j], s0);
    atomicAdd(&aff_all[(size_t)l * BSZ * AFF + AFF + j], s1);
}

// ---------------- [fused prev-attn out] + residual update + rmsnorm + mod ----------------
__global__ void k_addrmsmod(const float* __restrict__ hin, const float* __restrict__ raw,
                            const float* __restrict__ bias, const float* __restrict__ affprev,
                            float* __restrict__ residual, const float* __restrict__ normw,
                            const float* __restrict__ affcur,
                            float* __restrict__ hidden_n, unsigned short* __restrict__ u,
                            int has_raw) {
    __shared__ float s4[4];
    int row = blockIdx.x;
    int b = row >> 9;
    const float* hp = hin + (size_t)row * D_MODEL;
    float* rp = residual + (size_t)row * D_MODEL;
    float v[3]; float ss = 0.f;
    #pragma unroll
    for (int j = 0; j < 3; j++) {
        int d = threadIdx.x + j * 256;
        float x = hp[d];
        if (has_raw) {
            float g = affprev[b * AFF + 3840 + d];
            x += g * (raw[(size_t)row * D_MODEL + d] + bias[d]);
        }
        x += rp[d];
        rp[d] = x; v[j] = x; ss += x * x;
    }
    ss = block_sum_256(ss, s4);
    float inv = rsqrtf(ss / (float)D_MODEL + 1e-5f);
    const float* sh = affcur + b * AFF;
    const float* sc = affcur + b * AFF + 768;
    #pragma unroll
    for (int j = 0; j < 3; j++) {
        int d = threadIdx.x + j * 256;
        float hn = v[j] * inv * normw[d];
        hidden_n[(size_t)row * D_MODEL + d] = hn;
        u[(size_t)row * D_MODEL + d] = f2b(hn * (1.f + sc[d]) + sh[d]);
    }
}

// ---------------- depthwise causal conv + silu, fused softplus(dt) ----------------
__global__ void k_convdt(const float* __restrict__ zx, const float* __restrict__ convw,
                         const float* __restrict__ convb, const float* __restrict__ dtbias,
                         float* __restrict__ xBC, float* __restrict__ dtb) {
    int i = blockIdx.x * 256 + threadIdx.x;
    if (i < ROWS * NHEADS) {
        int h = i % NHEADS; int row = i / NHEADS;
        float x = zx[(size_t)row * D_IN_PROJ + D_INNER + CONV_DIM + h] + dtbias[h];
        dtb[i] = (x > 20.f) ? x : log1pf(expf(x));
    }
    if (i >= ROWS * CONV_DIM) return;
    int c = i % CONV_DIM; int row = i / CONV_DIM;
    int l = row & 511; int b = row >> 9;
    float acc = convb[c];
    #pragma unroll
    for (int k = 0; k < 4; k++) {
        int t = l - 3 + k;
        if (t >= 0)
            acc += convw[c * 4 + k] * zx[(size_t)(b * SEQ + t) * D_IN_PROJ + D_INNER + c];
    }
    xBC[i] = siluf(acc);
}

// ---------------- S1: per-chunk end state via MFMA ----------------
__global__ __launch_bounds__(256)
void k_ssm_state(const float* __restrict__ xBC, const float* __restrict__ dtb,
                 const float* __restrict__ Alog, float* __restrict__ Sbuf,
                 float* __restrict__ Pbuf) {
    int blk = blockIdx.x;
    int c = blk & (NCHUNK - 1); int bh = blk >> 3;
    int h = bh % NHEADS; int b = bh / NHEADS;
    int tid = threadIdx.x;
    __shared__ unsigned short sXwT[64][72];   // [p][t], scaled by w_t
    __shared__ unsigned short sBT[128][72];   // [n][t]
    __shared__ float sL[64], sDt[64];
    int base = b * SEQ + c * CT;
    int r = tid >> 2, q4 = tid & 3;
    if (tid < 64) {
        float dt = dtb[(base + tid) * NHEADS + h];
        float a = expf(Alog[h]);
        float v = -a * dt;
        #pragma unroll
        for (int off = 1; off < 64; off <<= 1) {
            float u2 = __shfl_up(v, off, 64);
            if (tid >= off) v += u2;
        }
        sL[tid] = v; sDt[tid] = dt;
    }
    __syncthreads();
    float Lend = sL[63];
    if (tid == 0) Pbuf[blk] = expf(Lend);
    float wr = expf(Lend - sL[r]) * sDt[r];
    const float* xrow = xBC + (size_t)(base + r) * CONV_DIM;
    #pragma unroll
    for (int j = 0; j < 4; j++) {
        float4 v = *(const float4*)&xrow[h * HEADDIM + q4 * 16 + j * 4];
        int p0 = q4 * 16 + j * 4;
        sXwT[p0 + 0][r] = f2b(v.x * wr); sXwT[p0 + 1][r] = f2b(v.y * wr);
        sXwT[p0 + 2][r] = f2b(v.z * wr); sXwT[p0 + 3][r] = f2b(v.w * wr);
    }
    #pragma unroll
    for (int j = 0; j < 8; j++) {
        float4 v = *(const float4*)&xrow[D_INNER + q4 * 32 + j * 4];
        int n0 = q4 * 32 + j * 4;
        sBT[n0 + 0][r] = f2b(v.x); sBT[n0 + 1][r] = f2b(v.y);
        sBT[n0 + 2][r] = f2b(v.z); sBT[n0 + 3][r] = f2b(v.w);
    }
    __syncthreads();
    int lane = tid & 63, wave = tid >> 6;
    int l15 = lane & 15, quad = lane >> 4;
    f32x4 acc[8];
    #pragma unroll
    for (int j = 0; j < 8; j++) acc[j] = (f32x4){0.f, 0.f, 0.f, 0.f};
    #pragma unroll
    for (int k0 = 0; k0 < 2; k0++) {
        bf16x8 a = *(const bf16x8*)&sXwT[wave * 16 + l15][k0 * 32 + quad * 8];
        #pragma unroll
        for (int nt = 0; nt < 8; nt++) {
            bf16x8 bv = *(const bf16x8*)&sBT[nt * 16 + l15][k0 * 32 + quad * 8];
            acc[nt] = __builtin_amdgcn_mfma_f32_16x16x32_bf16(a, bv, acc[nt], 0, 0, 0);
        }
    }
    float* sout = Sbuf + (size_t)blk * 8192;
    #pragma unroll
    for (int nt = 0; nt < 8; nt++) {
        int n = nt * 16 + l15;
        #pragma unroll
        for (int rr = 0; rr < 4; rr++) {
            int p = wave * 16 + quad * 4 + rr;
            sout[p * 128 + n] = acc[nt][rr];
        }
    }
}

// ---------------- S2: sequential chunk recurrence ----------------
__global__ void k_ssm_seq(const float* __restrict__ Sbuf, const float* __restrict__ Pbuf,
                          unsigned short* __restrict__ hstart) {
    int bh = blockIdx.x >> 5; int part = blockIdx.x & 31;
    int idx = part * 256 + threadIdx.x;
    float h = 0.f;
    #pragma unroll
    for (int c = 0; c < NCHUNK; c++) {
        size_t o = ((size_t)bh * NCHUNK + c) * 8192 + idx;
        hstart[o] = f2b(h);
        h = h * Pbuf[bh * NCHUNK + c] + Sbuf[o];
    }
}

// ---------------- S3: chunk outputs via MFMA ----------------
__global__ __launch_bounds__(256)
void k_ssm_out(const float* __restrict__ xBC, const float* __restrict__ dtb,
               const float* __restrict__ Alog, const float* __restrict__ Dssm,
               const unsigned short* __restrict__ hstart, float* __restrict__ y) {
    int blk = blockIdx.x;
    int c = blk & (NCHUNK - 1); int bh = blk >> 3;
    int h = bh % NHEADS; int b = bh / NHEADS;
    int tid = threadIdx.x;
    __shared__ unsigned short sB[64][136];    // [t][n]; reused for hstart [p][n]
    __shared__ unsigned short sC[64][136];    // [t][n]; scaled by exp(L_t) after pass 1
    __shared__ unsigned short sXT[64][72];    // [p][t]
    __shared__ unsigned short sG[64][72];     // [i][s]
    __shared__ float sL[64], sDt[64];
    int base = b * SEQ + c * CT;
    int r = tid >> 2, q4 = tid & 3;
    if (tid < 64) {
        float dt = dtb[(base + tid) * NHEADS + h];
        float a = expf(Alog[h]);
        float v = -a * dt;
        #pragma unroll
        for (int off = 1; off < 64; off <<= 1) {
            float u2 = __shfl_up(v, off, 64);
            if (tid >= off) v += u2;
        }
        sL[tid] = v; sDt[tid] = dt;
    }
    const float* xrow = xBC + (size_t)(base + r) * CONV_DIM;
    #pragma unroll
    for (int j = 0; j < 8; j++) {
        float4 v = *(const float4*)&xrow[D_INNER + q4 * 32 + j * 4];
        int n0 = q4 * 32 + j * 4;
        ushort4 pk; pk.x = f2b(v.x); pk.y = f2b(v.y); pk.z = f2b(v.z); pk.w = f2b(v.w);
        *(ushort4*)&sB[r][n0] = pk;
        float4 w = *(const float4*)&xrow[D_INNER + D_STATE + q4 * 32 + j * 4];
        ushort4 pk2; pk2.x = f2b(w.x); pk2.y = f2b(w.y); pk2.z = f2b(w.z); pk2.w = f2b(w.w);
        *(ushort4*)&sC[r][n0] = pk2;
    }
    #pragma unroll
    for (int j = 0; j < 4; j++) {
        float4 v = *(const float4*)&xrow[h * HEADDIM + q4 * 16 + j * 4];
        int p0 = q4 * 16 + j * 4;
        sXT[p0 + 0][r] = f2b(v.x); sXT[p0 + 1][r] = f2b(v.y);
        sXT[p0 + 2][r] = f2b(v.z); sXT[p0 + 3][r] = f2b(v.w);
    }
    const unsigned short* hsrc = hstart + ((size_t)bh * NCHUNK + c) * 8192;
    uint4 hreg[4];
    #pragma unroll
    for (int j = 0; j < 4; j++)
        hreg[j] = *(const uint4*)&hsrc[r * 128 + q4 * 32 + j * 8];
    __syncthreads();

    int lane = tid & 63, wave = tid >> 6;
    int l15 = lane & 15, quad = lane >> 4;
    f32x4 acc1[4];
    #pragma unroll
    for (int j = 0; j < 4; j++) acc1[j] = (f32x4){0.f, 0.f, 0.f, 0.f};
    #pragma unroll
    for (int k0 = 0; k0 < 4; k0++) {
        bf16x8 a = *(const bf16x8*)&sC[wave * 16 + l15][k0 * 32 + quad * 8];
        #pragma unroll
        for (int nt = 0; nt < 4; nt++) {
            bf16x8 bv = *(const bf16x8*)&sB[nt * 16 + l15][k0 * 32 + quad * 8];
            acc1[nt] = __builtin_amdgcn_mfma_f32_16x16x32_bf16(a, bv, acc1[nt], 0, 0, 0);
        }
    }
    #pragma unroll
    for (int nt = 0; nt < 4; nt++) {
        int s = nt * 16 + l15;
        float Ls = sL[s], dts = sDt[s];
        #pragma unroll
        for (int rr = 0; rr < 4; rr++) {
            int i = wave * 16 + quad * 4 + rr;
            float g = (s <= i) ? acc1[nt][rr] * expf(sL[i] - Ls) * dts : 0.f;
            sG[i][s] = f2b(g);
        }
    }
    {
        int row = wave * 16 + l15;
        float el = expf(sL[row]);
        #pragma unroll
        for (int j = 0; j < 32; j++) {
            int n = quad * 32 + j;
            sC[row][n] = f2b(b2f(sC[row][n]) * el);
        }
    }
    __syncthreads();
    #pragma unroll
    for (int j = 0; j < 4; j++)
        *(uint4*)&sB[r][q4 * 32 + j * 8] = hreg[j];
    __syncthreads();

    f32x4 acc2[4];
    #pragma unroll
    for (int j = 0; j < 4; j++) acc2[j] = (f32x4){0.f, 0.f, 0.f, 0.f};
    #pragma unroll
    for (int k0 = 0; k0 < 2; k0++) {
        bf16x8 a = *(const bf16x8*)&sG[wave * 16 + l15][k0 * 32 + quad * 8];
        #pragma unroll
        for (int nt = 0; nt < 4; nt++) {
            bf16x8 bv = *(const bf16x8*)&sXT[nt * 16 + l15][k0 * 32 + quad * 8];
            acc2[nt] = __builtin_amdgcn_mfma_f32_16x16x32_bf16(a, bv, acc2[nt], 0, 0, 0);
        }
    }
    #pragma unroll
    for (int k0 = 0; k0 < 4; k0++) {
        bf16x8 a = *(const bf16x8*)&sC[wave * 16 + l15][k0 * 32 + quad * 8];
        #pragma unroll
        for (int nt = 0; nt < 4; nt++) {
            bf16x8 bv = *(const bf16x8*)&sB[nt * 16 + l15][k0 * 32 + quad * 8];
            acc2[nt] = __builtin_amdgcn_mfma_f32_16x16x32_bf16(a, bv, acc2[nt], 0, 0, 0);
        }
    }
    float Dh = Dssm[h];
    #pragma unroll
    for (int nt = 0; nt < 4; nt++) {
        int p = nt * 16 + l15;
        #pragma unroll
        for (int rr = 0; rr < 4; rr++) {
            int i = wave * 16 + quad * 4 + rr;
            float xv = b2f(sXT[p][i]);
            y[(size_t)(base + i) * D_INNER + h * HEADDIM + p] = acc2[nt][rr] + Dh * xv;
        }
    }
}

// ---------------- gated rmsnorm -> bf16 ----------------
__global__ void k_gatednorm(const float* __restrict__ yscan, const float* __restrict__ zx,
                            const float* __restrict__ nw, unsigned short* __restrict__ out) {
    __shared__ float s4[4];
    int row = blockIdx.x;
    const float* yp = yscan + (size_t)row * D_INNER;
    const float* zp = zx + (size_t)row * D_IN_PROJ;
    float v[6]; float ss = 0.f;
    #pragma unroll
    for (int j = 0; j < 6; j++) {
        int d = threadIdx.x + j * 256;
        float val = yp[d] * siluf(zp[d]);
        v[j] = val; ss += val * val;
    }
    ss = block_sum_256(ss, s4);
    float inv = rsqrtf(ss / (float)D_INNER + 1e-5f);
    #pragma unroll
    for (int j = 0; j < 6; j++) {
        int d = threadIdx.x + j * 256;
        out[(size_t)row * D_INNER + d] = f2b(v[j] * inv * nw[d]);
    }
}

// ---------------- hidden2 = hidden_n + g_mba*(tmp+out_b); ln_noaffine + msa mod -> bf16 ----
__global__ void k_fuse_ln(const float* __restrict__ hidden_n, const float* __restrict__ tmp,
                          const float* __restrict__ outb, const float* __restrict__ aff,
                          float* __restrict__ hidden2, unsigned short* __restrict__ attnx) {
    __shared__ float s4[4];
    int row = blockIdx.x;
    int b = row >> 9;
    const float* gm = aff + b * AFF + 1536;
    float v[3]; float s = 0.f;
    #pragma unroll
    for (int j = 0; j < 3; j++) {
        int d = threadIdx.x + j * 256;
        float x = hidden_n[(size_t)row * D_MODEL + d]
                + gm[d] * (tmp[(size_t)row * D_MODEL + d] + outb[d]);
        hidden2[(size_t)row * D_MODEL + d] = x;
        v[j] = x; s += x;
    }
    float mean = block_sum_256(s, s4) / (float)D_MODEL;
    float ss = 0.f;
    #pragma unroll
    for (int j = 0; j < 3; j++) { float c = v[j] - mean; ss += c * c; }
    float var = block_sum_256(ss, s4) / (float)D_MODEL;
    float inv = rsqrtf(var + 1e-6f);
    const float* sh = aff + b * AFF + 2304;
    const float* sc = aff + b * AFF + 3072;
    #pragma unroll
    for (int j = 0; j < 3; j++) {
        int d = threadIdx.x + j * 256;
        float xh = (v[j] - mean) * inv;
        attnx[(size_t)row * D_MODEL + d] = f2b(xh * (1.f + sc[d]) + sh[d]);
    }
}

// ---------------- cross-attention, LDS-tiled: block per (b,h,32-query tile) ----------------
__global__ __launch_bounds__(256)
void k_attn(const float* __restrict__ qb, const unsigned short* __restrict__ kb,
            const unsigned short* __restrict__ vb, unsigned short* __restrict__ ob) {
    int blk = blockIdx.x;
    int lt = blk & 15; int h = (blk >> 4) & 7; int b = blk >> 7;
    __shared__ unsigned short sK[64][66];
    __shared__ unsigned short sV[64][66];
    __shared__ float sQ[32][65];
    int tid = threadIdx.x;
    {
        int r = tid >> 2, c0 = (tid & 3) * 16;
        const unsigned short* kp = kb + (size_t)(b * LC + r) * AINNER + h * AD + c0;
        const unsigned short* vp = vb + (size_t)(b * LC + r) * AINNER + h * AD + c0;
        #pragma unroll
        for (int j = 0; j < 4; j++) {
            *(ushort4*)&sK[r][c0 + j * 4] = *(const ushort4*)&kp[j * 4];
            *(ushort4*)&sV[r][c0 + j * 4] = *(const ushort4*)&vp[j * 4];
        }
    }
    {
        int r = tid >> 3, c0 = (tid & 7) * 8;
        const float* qp = qb + (size_t)(b * SEQ + lt * 32 + r) * AINNER + h * AD + c0;
        #pragma unroll
        for (int j = 0; j < 2; j++)
            *(float4*)&sQ[r][c0 + j * 4] = *(const float4*)&qp[j * 4];
    }
    __syncthreads();
    int wave = tid >> 6, m = tid & 63;
    #pragma unroll
    for (int qq = 0; qq < 8; qq++) {
        int q = wave * 8 + qq;
        float s = 0.f;
        #pragma unroll 8
        for (int d = 0; d < AD; d++) s += sQ[q][d] * b2f(sK[m][d]);
        s *= 0.125f;
        float mx = s;
        #pragma unroll
        for (int off = 32; off > 0; off >>= 1) mx = fmaxf(mx, __shfl_xor(mx, off, 64));
        float e = expf(s - mx);
        float sum = e;
        #pragma unroll
        for (int off = 32; off > 0; off >>= 1) sum += __shfl_xor(sum, off, 64);
        float a = e / sum;
        float acc = 0.f;
        #pragma unroll 8
        for (int mm = 0; mm < LC; mm++) {
            float am = __shfl(a, mm, 64);
            acc += am * b2f(sV[mm][m]);
        }
        ob[(size_t)(b * SEQ + lt * 32 + q) * AINNER + h * AD + m] = f2b(acc);
    }
}

// ---------------- final: h = hidden2 + g*(raw+bias); rmsnorm(h + r) ----------------
__global__ void k_final(const float* __restrict__ hidden2, const float* __restrict__ raw,
                        const float* __restrict__ bias, const float* __restrict__ aff,
                        const float* __restrict__ residual, const float* __restrict__ w,
                        float* __restrict__ out) {
    __shared__ float s4[4];
    int row = blockIdx.x;
    int b = row >> 9;
    const float* gm = aff + b * AFF + 3840;
    float v[3]; float ss = 0.f;
    #pragma unroll
    for (int j = 0; j < 3; j++) {
        int d = threadIdx.x + j * 256;
        float x = hidden2[(size_t)row * D_MODEL + d]
                + gm[d] * (raw[(size_t)row * D_MODEL + d] + bias[d])
                + residual[(size_t)row * D_MODEL + d];
        v[j] = x; ss += x * x;
    }
    ss = block_sum_256(ss, s4);
    float inv = rsqrtf(ss / (float)D_MODEL + 1e-5f);
    #pragma unroll
    for (int j = 0; j < 3; j++) {
        int d = threadIdx.x + j * 256;
        out[(size_t)row * D_MODEL + d] = v[j] * inv * w[d];
    }
}

// ---------------- host launch ----------------
extern "C" void kernel_launch(void* const* d_in, const int* in_sizes, int n_in,
                              void* d_out, int out_size, void* d_ws, size_t ws_size,
                              hipStream_t stream) {
    const float* hidden_states = (const float*)d_in[0];
    const float* ref_emb  = (const float*)d_in[1];
    const float* norm_w   = (const float*)d_in[2];
    const float* ada_w    = (const float*)d_in[3];
    const float* ada_b    = (const float*)d_in[4];
    const float* in_w     = (const float*)d_in[5];
    const float* conv_w   = (const float*)d_in[6];
    const float* conv_b   = (const float*)d_in[7];
    const float* dt_bias  = (const float*)d_in[8];
    const float* A_log    = (const float*)d_in[9];
    const float* D_ssm    = (const float*)d_in[10];
    const float* ssm_nw   = (const float*)d_in[11];
    const float* out_w    = (const float*)d_in[12];
    const float* out_b    = (const float*)d_in[13];
    const float* q_w      = (const float*)d_in[14];
    const float* k_w      = (const float*)d_in[15];
    const float* v_w      = (const float*)d_in[16];
    const float* o_w      = (const float*)d_in[17];
    const float* o_b      = (const float*)d_in[18];
    const float* norm_f_w = (const float*)d_in[19];
    float* out = (float*)d_out;

    char* p = (char*)d_ws;
    auto alloc = [&](size_t bytes) -> char* {
        char* r = p; p += (bytes + 255) & ~(size_t)255; return r;
    };
    float* residual = (float*)alloc((size_t)ROWS * D_MODEL * 4);
    float* hidden2  = (float*)alloc((size_t)ROWS * D_MODEL * 4);
    float* hidden_n = (float*)alloc((size_t)ROWS * D_MODEL * 4);
    float* tmp      = (float*)alloc((size_t)ROWS * D_MODEL * 4);
    float* zx       = (float*)alloc((size_t)ROWS * D_IN_PROJ * 4);
    float* xBC      = (float*)alloc((size_t)ROWS * CONV_DIM * 4);
    float* dtb      = (float*)alloc((size_t)ROWS * NHEADS * 4);
    float* yscan    = (float*)alloc((size_t)ROWS * D_INNER * 4);
    float* qb       = (float*)alloc((size_t)ROWS * AINNER * 4);
    float* aff_all  = (float*)alloc((size_t)N_LAYER * BSZ * AFF * 4);
    float* smc      = (float*)alloc((size_t)BSZ * D_MODEL * 4);
    float* Sbuf     = (float*)alloc((size_t)BSZ * NHEADS * NCHUNK * 8192 * 4);
    float* Pbuf     = (float*)alloc((size_t)BSZ * NHEADS * NCHUNK * 4);
    unsigned short* hstart = (unsigned short*)alloc((size_t)BSZ * NHEADS * NCHUNK * 8192 * 2);
    unsigned short* u_bf   = (unsigned short*)alloc((size_t)ROWS * D_MODEL * 2);
    unsigned short* ynorm  = (unsigned short*)alloc((size_t)ROWS * D_INNER * 2);
    unsigned short* attnx  = (unsigned short*)alloc((size_t)ROWS * D_MODEL * 2);
    unsigned short* ob     = (unsigned short*)alloc((size_t)ROWS * AINNER * 2);
    unsigned short* ref_bf = (unsigned short*)alloc((size_t)BSZ * LC * D_MODEL * 2);
    unsigned short* kb_all  = (unsigned short*)alloc((size_t)N_LAYER * BSZ * LC * AINNER * 2);
    unsigned short* vb_all  = (unsigned short*)alloc((size_t)N_LAYER * BSZ * LC * AINNER * 2);
    unsigned short* in_wt_all  = (unsigned short*)alloc((size_t)N_LAYER * NP1 * D_MODEL * 2);
    unsigned short* out_wt_all = (unsigned short*)alloc((size_t)N_LAYER * D_MODEL * D_INNER * 2);
    unsigned short* q_wt_all   = (unsigned short*)alloc((size_t)N_LAYER * AINNER * D_MODEL * 2);
    unsigned short* o_wt_all   = (unsigned short*)alloc((size_t)N_LAYER * D_MODEL * AINNER * 2);
    unsigned short* kwt_all = (unsigned short*)alloc((size_t)N_LAYER * AINNER * D_MODEL * 2);
    unsigned short* vwt_all = (unsigned short*)alloc((size_t)N_LAYER * AINNER * D_MODEL * 2);

    hipMemsetAsync(residual, 0, (size_t)ROWS * D_MODEL * sizeof(float), stream);
    k_silumean<<<(BSZ * D_MODEL + 255) / 256, 256, 0, stream>>>(ref_emb, smc);
    k_f2b<<<(BSZ * LC * D_MODEL + 255) / 256, 256, 0, stream>>>(ref_emb, ref_bf, BSZ * LC * D_MODEL);
    k_ada_init<<<(N_LAYER * BSZ * AFF + 255) / 256, 256, 0, stream>>>(ada_b, aff_all);
    k_ada_split<<<dim3(AFF / 256, 8, N_LAYER), 256, 0, stream>>>(smc, ada_w, aff_all);

    // all weight transposes, batched over layers, hoisted out of the loop
    k_transpose_pb<<<dim3(NP1 / 32, D_MODEL / 32, N_LAYER), 256, 0, stream>>>(in_w, in_wt_all, D_MODEL, D_IN_PROJ, NP1);
    k_transpose_pb<<<dim3(D_MODEL / 32, D_INNER / 32, N_LAYER), 256, 0, stream>>>(out_w, out_wt_all, D_INNER, D_MODEL, D_MODEL);
    k_transpose_pb<<<dim3(AINNER / 32, D_MODEL / 32, N_LAYER), 256, 0, stream>>>(q_w, q_wt_all, D_MODEL, AINNER, AINNER);
    k_transpose_pb<<<dim3(D_MODEL / 32, AINNER / 32, N_LAYER), 256, 0, stream>>>(o_w, o_wt_all, AINNER, D_MODEL, D_MODEL);
    k_transpose_pb<<<dim3(AINNER / 32, D_MODEL / 32, N_LAYER), 256, 0, stream>>>(k_w, kwt_all, D_MODEL, AINNER, AINNER);
    k_transpose_pb<<<dim3(AINNER / 32, D_MODEL / 32, N_LAYER), 256, 0, stream>>>(v_w, vwt_all, D_MODEL, AINNER, AINNER);
    k_gemm_kv<<<dim3(AINNER / 128, 1, N_LAYER * 2), 256, 0, stream>>>(ref_bf, kwt_all, vwt_all, kb_all, vb_all);

    for (int layer = 0; layer < N_LAYER; layer++) {
        const float* L_norm_w  = norm_w  + layer * D_MODEL;
        const float* L_conv_w  = conv_w  + layer * CONV_DIM * 4;
        const float* L_conv_b  = conv_b  + layer * CONV_DIM;
        const float* L_dt_bias = dt_bias + layer * NHEADS;
        const float* L_A_log   = A_log   + layer * NHEADS;
        const float* L_D_ssm   = D_ssm   + layer * NHEADS;
        const float* L_ssm_nw  = ssm_nw  + layer * D_INNER;
        const float* L_out_b   = out_b   + layer * D_MODEL;
        const float* L_o_b_prev= o_b     + (layer - 1) * D_MODEL;
        const float* L_aff     = aff_all + (size_t)layer * BSZ * AFF;
        const float* L_aff_prev= aff_all + (size_t)(layer - 1) * BSZ * AFF;
        const unsigned short* in_wt  = in_wt_all  + (size_t)layer * NP1 * D_MODEL;
        const unsigned short* out_wt = out_wt_all + (size_t)layer * D_MODEL * D_INNER;
        const unsigned short* q_wt   = q_wt_all   + (size_t)layer * AINNER * D_MODEL;
        const unsigned short* o_wt   = o_wt_all   + (size_t)layer * D_MODEL * AINNER;

        k_addrmsmod<<<ROWS, 256, 0, stream>>>(
            layer == 0 ? hidden_states : hidden2, tmp,
            layer == 0 ? o_b : L_o_b_prev,
            layer == 0 ? aff_all : L_aff_prev,
            residual, L_norm_w, L_aff, hidden_n, u_bf, layer == 0 ? 0 : 1);
        k_gemm<<<dim3(NP1 / 128, ROWS / 128), 256, 0, stream>>>(u_bf, in_wt, zx, ROWS, D_IN_PROJ, D_MODEL);
        k_convdt<<<(ROWS * CONV_DIM + 255) / 256, 256, 0, stream>>>(zx, L_conv_w, L_conv_b, L_dt_bias, xBC, dtb);
        k_ssm_state<<<BSZ * NHEADS * NCHUNK, 256, 0, stream>>>(xBC, dtb, L_A_log, Sbuf, Pbuf);
        k_ssm_seq<<<BSZ * NHEADS * 32, 256, 0, stream>>>(Sbuf, Pbuf, hstart);
        k_ssm_out<<<BSZ * NHEADS * NCHUNK, 256, 0, stream>>>(xBC, dtb, L_A_log, L_D_ssm, hstart, yscan);
        k_gatednorm<<<ROWS, 256, 0, stream>>>(yscan, zx, L_ssm_nw, ynorm);
        k_gemm<<<dim3(D_MODEL / 128, ROWS / 128), 256, 0, stream>>>(ynorm, out_wt, tmp, ROWS, D_MODEL, D_INNER);
        k_fuse_ln<<<ROWS, 256, 0, stream>>>(hidden_n, tmp, L_out_b, L_aff, hidden2, attnx);
        k_gemm<<<dim3(AINNER / 128, ROWS / 128), 256, 0, stream>>>(attnx, q_wt, qb, ROWS, AINNER, D_MODEL);
        k_attn<<<BSZ * AH * 16, 256, 0, stream>>>(
            qb, kb_all + (size_t)layer * BSZ * LC * AINNER,
            vb_all + (size_t)layer * BSZ * LC * AINNER, ob);
        k_gemm<<<dim3(D_MODEL / 128, ROWS / 128), 256, 0, stream>>>(ob, o_wt, tmp, ROWS, D_MODEL, AINNER);
    }
    k_final<<<ROWS, 256, 0, stream>>>(hidden2, tmp, o_b + (N_LAYER - 1) * D_MODEL,
                                      aff_all + (size_t)(N_LAYER - 1) * BSZ * AFF,
                                      residual, norm_f_w, out);
}